// Round 17
// baseline (376.258 us; speedup 1.0000x reference)
//
#include <hip/hip_runtime.h>
#include <hip/hip_bf16.h>
#include <stdint.h>

#define NND 12000
#define DM  256
#define KNN 16
#define NB  4096          // x-buckets
#define BW  0.00390625f   // bucket width = 1/256 over [-8, 8)
#define RW  16            // fixed-window rounds (16*64 = 1024 candidates)
#define NWELEM 360448     // total weight elements converted to bf16 hi/lo
#define KBLK (NND/4)      // 3000 knn blocks first (r32 ordering, measured best)

// Opaque register barrier: prevents FMA contraction (r9: made knn bit-match numpy
// -> absmax 0.0. DO NOT REMOVE from knn path).
#define FPBAR(x) asm volatile("" : "+v"(x))

typedef unsigned long long u64;
typedef __attribute__((ext_vector_type(8))) short bf8_t;   // 8 bf16 (4 VGPRs)
typedef __attribute__((ext_vector_type(4))) float f4_t;

__device__ __forceinline__ float geluf(float x){ return 0.5f*x*(1.0f + erff(x*0.70710678118654752f)); }
__device__ __forceinline__ int bucketof(float x){
  int b = (int)floorf((x + 8.0f) * 256.0f);
  return min(max(b, 0), NB-1);
}

__device__ __forceinline__ unsigned short bf16_rne(float x){
  unsigned u = __float_as_uint(x);
  unsigned r = u + 0x7FFF + ((u >> 16) & 1);
  return (unsigned short)(r >> 16);
}

__device__ __forceinline__ float bfpair(unsigned short h, unsigned short l){
  return __uint_as_float(((unsigned)h) << 16) + __uint_as_float(((unsigned)l) << 16);
}

// async global->LDS, 16B per lane. LDS dest is WAVE-UNIFORM base + lane*16;
// global src is per-lane. Completion tracked by vmcnt.
__device__ __forceinline__ void gload16(const unsigned short* g, unsigned short* l){
  __builtin_amdgcn_global_load_lds(
      (__attribute__((address_space(1))) void*)g,
      (__attribute__((address_space(3))) void*)l, 16, 0, 0);
}

// bit-exact numpy distance key (r9-verified). Low 32 bits = original node idx.
__device__ __forceinline__ u64 make_key(float xi, float yi, float sqi,
                                        float cx, float cy, int jd, int self){
  float ax = cx*cx;  FPBAR(ax);
  float ay = cy*cy;  FPBAR(ay);
  float sqj = ax + ay;   FPBAR(sqj);
  float px = xi*cx;    FPBAR(px);
  float py = yi*cy;    FPBAR(py);
  float dt = px + py;    FPBAR(dt);            // NO-FMA dot
  float two_dt = 2.0f*dt;  FPBAR(two_dt);
  float ss = sqi + sqj;    FPBAR(ss);
  float d2 = ss - two_dt;  FPBAR(d2);
  float dist = __fsqrt_rn(fmaxf(d2, 0.0f));
  u64 key = ((u64)__float_as_uint(dist) << 32) | (unsigned)jd;
  return (jd == self) ? ~0ULL : key;
}

__device__ __forceinline__ void ladder_insert(u64* L, u64 key){
  bool c[KNN];
  #pragma unroll
  for (int t=0;t<KNN;t++) c[t] = key < L[t];
  #pragma unroll
  for (int t=KNN-1;t>=1;t--) L[t] = c[t-1] ? L[t-1] : (c[t] ? key : L[t]);
  L[0] = c[0] ? key : L[0];
}

// merge 64 candidate keys (one per lane) -> lane r holds r-th smallest (r<16).
__device__ __forceinline__ u64 merge64(const u64* m, int lane)
{
  u64 cur = m[lane];
  u64 out16 = ~0ULL;
  for (int r=0;r<KNN;r++){
    u64 k = cur; int who = lane;
    #pragma unroll
    for (int o=32;o>0;o>>=1){
      u64 ok = __shfl_xor(k, o, 64);
      int ow = __shfl_xor(who, o, 64);
      if (ok < k){ k = ok; who = ow; }
    }
    if (lane == r) out16 = k;
    if (lane == who) cur = ~0ULL;
  }
  return out16;
}

__device__ __forceinline__ void write_outputs(u64 out16, int lane, int n,
    int* __restrict__ idx_out, float* __restrict__ w_out)
{
  if (lane < KNN) idx_out[(size_t)n*KNN + lane] = (int)(unsigned)(out16 & 0xFFFFFFFFull);
  u64 kt[KNN];
  #pragma unroll
  for (int t=0;t<KNN;t++) kt[t] = __shfl(out16, t, 64);
  float inv[KNN];
  #pragma unroll
  for (int t=0;t<KNN;t++){
    float d = __uint_as_float((unsigned)(kt[t] >> 32));
    inv[t] = __fdiv_rn(1.0f, fmaxf(d, 1e-4f));
  }
  float r8v[8];
  #pragma unroll
  for (int t=0;t<8;t++){ r8v[t] = inv[t] + inv[t+8]; FPBAR(r8v[t]); }
  float s01 = r8v[0]+r8v[1]; FPBAR(s01);
  float s23 = r8v[2]+r8v[3]; FPBAR(s23);
  float s45 = r8v[4]+r8v[5]; FPBAR(s45);
  float s67 = r8v[6]+r8v[7]; FPBAR(s67);
  float sA = s01+s23; FPBAR(sA);
  float sB = s45+s67; FPBAR(sB);
  float s = sA + sB;
  s = fmaxf(s, 1e-8f);
  if (lane < KNN){
    float d = __uint_as_float((unsigned)(out16 >> 32));
    float invL = __fdiv_rn(1.0f, fmaxf(d, 1e-4f));
    w_out[(size_t)n*KNN + lane] = __fdiv_rn(invL, s);
  }
}

// compare-exchange macros for the bitonic network (named scalars only —
// r20/r28 lesson: u64 ARRAYS mutated through pointers/under exec-mask get
// lowered to scratch (VGPR 28/32 signatures). Named scalars stay in regs.
#define CE_A(x,y) { u64 mn_=(x)<(y)?(x):(y); u64 mx_=(x)<(y)?(y):(x); (x)=mn_; (y)=mx_; }
#define CE_D(x,y) { u64 mn_=(x)<(y)?(x):(y); u64 mx_=(x)<(y)?(y):(x); (x)=mx_; (y)=mn_; }

// LDS-free ballot tournament over NAMED scalars K0..K15 (r28/r30-proven).
#define TOURNEY16(out16, lane) {                                   \
    u64 cur = K0;                                                  \
    for (int r_=0;r_<KNN;r_++){                                    \
      u64 k_ = cur;                                                \
      _Pragma("unroll")                                            \
      for (int o_=32;o_>0;o_>>=1){                                 \
        u64 ok_ = __shfl_xor(k_, o_, 64);                          \
        if (ok_ < k_) k_ = ok_;                                    \
      }                                                            \
      u64 ball_ = __ballot(cur == k_);                             \
      int who_ = __ffsll(ball_) - 1;                               \
      if ((lane) == r_) out16 = k_;                                \
      if ((lane) == who_){                                         \
        K0=K1; K1=K2; K2=K3; K3=K4; K4=K5; K5=K6; K6=K7; K7=K8;    \
        K8=K9; K9=K10; K10=K11; K11=K12; K12=K13; K13=K14;         \
        K14=K15; K15=~0ULL;                                        \
        cur = K0;                                                  \
      }                                                            \
    }                                                              \
  }

// ---------------- dtype detection (proven: picks f32 here) ----------------
__global__ __launch_bounds__(256) void detect_kernel_r35(
    const unsigned* __restrict__ a, int na,
    const unsigned* __restrict__ b, int nb, int* __restrict__ flag)
{
  __shared__ int cnt;
  if (threadIdx.x == 0) cnt = 0;
  __syncthreads();
  int c = 0;
  for (int i = threadIdx.x; i < na; i += 256){
    int ex = (a[i] >> 7) & 0xFF;
    c += (ex >= 113 && ex <= 131) ? 1 : 0;
  }
  for (int i = threadIdx.x; i < nb; i += 256){
    int ex = (b[i] >> 7) & 0xFF;
    c += (ex >= 113 && ex <= 131) ? 1 : 0;
  }
  atomicAdd(&cnt, c);
  __syncthreads();
  if (threadIdx.x == 0) *flag = (cnt > (na + nb) / 2) ? 1 : 0;
}

// ---------------- decode all inputs (fused weight hi/lo split; r34-proven) ----------------
struct SegTable {
  const void* src[16];
  float*      dst[16];
  int         cnt[16];
  int         wofs[16];   // >=0: offset into wh/wl for weight segs, else -1
  int         total;
};

__global__ __launch_bounds__(256) void decode_kernel_r35(SegTable t,
    unsigned short* __restrict__ fh, unsigned short* __restrict__ fl,
    unsigned short* __restrict__ dh, unsigned short* __restrict__ dl,
    const int* __restrict__ flag)
{
  const int is_bf16 = *flag;
  for (int e = blockIdx.x*256 + threadIdx.x; e < t.total; e += gridDim.x*256){
    int rem = e, s = 0;
    while (rem >= t.cnt[s]){ rem -= t.cnt[s]; ++s; }
    float v;
    if (is_bf16) v = __uint_as_float(((unsigned)((const unsigned short*)t.src[s])[rem]) << 16);
    else         v = ((const float*)t.src[s])[rem];
    if (s == 0){
      unsigned short hb = bf16_rne(v);
      float hf = __uint_as_float(((unsigned)hb) << 16);
      fh[rem] = hb;
      fl[rem] = bf16_rne(v - hf);
    } else {
      int wo = t.wofs[s];
      if (wo >= 0){
        unsigned short hb = bf16_rne(v);
        float hf = __uint_as_float(((unsigned)hb) << 16);
        dh[wo + rem] = hb;
        dl[wo + rem] = bf16_rne(v - hf);
      } else {
        t.dst[s][rem] = v;
      }
    }
  }
}

// ---------------- bucket pre-pass ----------------
__global__ __launch_bounds__(256) void zero_kernel_r35(int* __restrict__ hist, int* __restrict__ cursor,
                                                       int* __restrict__ ocnt)
{
  int t = blockIdx.x*256 + threadIdx.x;
  if (t < NB){ hist[t] = 0; cursor[t] = 0; }
  if (blockIdx.x == 0 && threadIdx.x == 0) *ocnt = 0;
}

__global__ __launch_bounds__(256) void count_kernel_r35(const float* __restrict__ cents,
                                                        int* __restrict__ hist)
{
  int i = blockIdx.x*256 + threadIdx.x;
  if (i < NND) atomicAdd(&hist[bucketof(cents[2*i])], 1);
}

__global__ __launch_bounds__(1024) void scan_kernel_r35(const int* __restrict__ hist,
                                                        int* __restrict__ offs)
{
  __shared__ int s[1024];
  int t = threadIdx.x;
  int h0 = hist[t*4], h1 = hist[t*4+1], h2 = hist[t*4+2], h3 = hist[t*4+3];
  int tot = h0+h1+h2+h3;
  s[t] = tot;
  __syncthreads();
  for (int d=1; d<1024; d<<=1){
    int v = (t >= d) ? s[t-d] : 0;
    __syncthreads();
    s[t] += v;
    __syncthreads();
  }
  int excl = s[t] - tot;
  offs[t*4]   = excl;
  offs[t*4+1] = excl + h0;
  offs[t*4+2] = excl + h0 + h1;
  offs[t*4+3] = excl + h0 + h1 + h2;
}

// r35: scatter packs (x, y, bitcast(id)) into ONE float4 -> knn collect loads
// 1x16B per candidate instead of 8B+4B (two instructions). Same bit values ->
// bit-exact keys.
__global__ __launch_bounds__(256) void scatter_kernel_r35(const float* __restrict__ cents,
    const int* __restrict__ offs, int* __restrict__ cursor,
    float4* __restrict__ sxyid)
{
  int i = blockIdx.x*256 + threadIdx.x;
  if (i < NND){
    float x = cents[2*i], y = cents[2*i+1];
    int b = bucketof(x);
    int pos = offs[b] + atomicAdd(&cursor[b], 1);
    sxyid[pos] = make_float4(x, y, __int_as_float(i), 0.f);
  }
}

// ---------------- FUSED: encoder GEMM (blocks >= KBLK) || knn_fixed (blocks < KBLK) ----------------
// r32-proven structure; r35: knn candidate loads via packed float4.
__global__ __launch_bounds__(256, 4) void fused_enc_knn_r35(
    // encoder args
    const unsigned short* __restrict__ A1h, const unsigned short* __restrict__ A1l,
    const unsigned short* __restrict__ W1h, const unsigned short* __restrict__ W1l,
    const float* __restrict__ bias,
    unsigned short* __restrict__ Ch, unsigned short* __restrict__ Cl,
    // knn args
    const float4* __restrict__ sxyid,
    const float* __restrict__ cents, const int* __restrict__ offs,
    int* __restrict__ idx_out, float* __restrict__ w_out,
    int* __restrict__ ocnt, int* __restrict__ olist, float* __restrict__ othr)
{
  __shared__ unsigned short sbW[3][2][2048];   // 24KB, encoder path only
  const int lane = threadIdx.x & 63, wv = threadIdx.x >> 6;

  if (blockIdx.x >= KBLK){
    // ================= encoder body (mm_mfma_r30 <256,false,true,true>) ===========
    constexpr int NW = 2, NA = 2;
    constexpr int NCG = 4, LG = 2;
    constexpr int RTM = (NND + 63) / 64;   // 188
    const int ebid = blockIdx.x - KBLK;
    const int xcd = ebid & 7;
    const int cg  = (ebid >> 3) & (NCG - 1);
    const int rt  = ((ebid >> (3 + LG)) << 3) + xcd;
    if (rt >= RTM) return;
    const int row0 = rt*64;
    const int n0 = cg*64;
    const int l15 = lane & 15;
    const int quad = lane >> 4;

    const size_t woff = (size_t)(n0 + lane) * DM;
    const unsigned short* wsrc = ((wv < 2) ? W1h : W1l) + woff;
    const int wtile = wv >> 1, q0 = (wv & 1) * 2;

    const int am = min(row0 + wv*16 + l15, NND-1);
    const size_t abase = (size_t)am*DM + quad*8;

    f4_t acc[4];
    #pragma unroll
    for (int t=0;t<4;t++) acc[t] = (f4_t){0.f,0.f,0.f,0.f};

    bf8_t A1H[3], A1L[3];

    auto STAGE = [&](int b, int ks){
      #pragma unroll
      for (int j=0;j<2;j++)
        gload16(wsrc + ks*32 + (q0+j)*8, &sbW[b][wtile][(q0+j)*512]);
    };
    auto LOADA = [&](int s, int ks){
      A1H[s] = *(const bf8_t*)(A1h + abase + ks*32);
      A1L[s] = *(const bf8_t*)(A1l + abase + ks*32);
    };

    STAGE(0, 0); LOADA(0, 0);
    STAGE(1, 1); LOADA(1, 1);
    constexpr int NKS = DM/32;             // 8
    #pragma unroll
    for (int ks=0; ks<NKS; ++ks){
      const int b = ks % 3;
      if (ks + 2 < NKS){ STAGE((ks+2)%3, ks+2); LOADA((ks+2)%3, ks+2); }
      if (ks + 2 < NKS)      asm volatile("s_waitcnt vmcnt(%0)" :: "i"(2*(NW+NA)) : "memory");
      else if (ks + 1 < NKS) asm volatile("s_waitcnt vmcnt(%0)" :: "i"(NW+NA) : "memory");
      else                   asm volatile("s_waitcnt vmcnt(0)" ::: "memory");
      __builtin_amdgcn_sched_barrier(0);
      __builtin_amdgcn_s_barrier();
      __builtin_amdgcn_sched_barrier(0);
      {
        bf8_t a1h = A1H[b], a1l = A1L[b];
        #pragma unroll
        for (int t=0;t<4;t++){
          const int wr = quad*512 + (t*16 + l15)*8;
          bf8_t bh = *(const bf8_t*)&sbW[b][0][wr];
          bf8_t bl = *(const bf8_t*)&sbW[b][1][wr];
          acc[t] = __builtin_amdgcn_mfma_f32_16x16x32_bf16(a1h, bh, acc[t], 0, 0, 0);
          acc[t] = __builtin_amdgcn_mfma_f32_16x16x32_bf16(a1h, bl, acc[t], 0, 0, 0);
          acc[t] = __builtin_amdgcn_mfma_f32_16x16x32_bf16(a1l, bh, acc[t], 0, 0, 0);
        }
      }
      __builtin_amdgcn_sched_barrier(0);
      asm volatile("s_waitcnt lgkmcnt(0)" ::: "memory");
      __builtin_amdgcn_s_barrier();
      __builtin_amdgcn_sched_barrier(0);
    }

    #pragma unroll
    for (int t=0;t<4;t++){
      int n = n0 + t*16 + l15;
      float bv = bias[n];
      #pragma unroll
      for (int r=0;r<4;r++){
        int row = row0 + wv*16 + quad*4 + r;
        if (row < NND){
          float v = geluf(acc[t][r] + bv);
          unsigned short hb = bf16_rne(v);
          float hf = __uint_as_float(((unsigned)hb) << 16);
          Ch[(size_t)row*DM + n] = hb;
          Cl[(size_t)row*DM + n] = bf16_rne(v - hf);
        }
      }
    }
    return;
  }

  // ================= knn_fixed body (r30 structure, packed float4 loads) =====
  const int n = blockIdx.x*4 + wv;
  const float xi = cents[2*n];
  const float yi = cents[2*n+1];
  float sx = xi*xi; FPBAR(sx);
  float sy = yi*yi; FPBAR(sy);
  float sqi = sx + sy; FPBAR(sqi);

  const int start = offs[bucketof(xi)];
  const bool isR = lane < 32;
  const int lo = isR ? lane : (lane - 32);

  u64 K0,K1,K2,K3,K4,K5,K6,K7,K8,K9,K10,K11,K12,K13,K14,K15;
  #define KROUND(r, K) { \
    int myp = isR ? (start + (r)*32 + lo) : (start - 1 - (r)*32 - lo); \
    bool act = (myp >= 0) && (myp < NND); \
    float4 cu = make_float4(0.f, 0.f, 0.f, 0.f); \
    int jd = -1; \
    if (act){ cu = sxyid[myp]; jd = __float_as_int(cu.z); } \
    u64 key = make_key(xi, yi, sqi, cu.x, cu.y, jd, n); \
    K = act ? key : ~0ULL; }
  KROUND(0,K0)   KROUND(1,K1)   KROUND(2,K2)   KROUND(3,K3)
  KROUND(4,K4)   KROUND(5,K5)   KROUND(6,K6)   KROUND(7,K7)
  KROUND(8,K8)   KROUND(9,K9)   KROUND(10,K10) KROUND(11,K11)
  KROUND(12,K12) KROUND(13,K13) KROUND(14,K14) KROUND(15,K15)
  #undef KROUND

  // bitonic sort network, 16 keys ascending (80 compare-exchanges, static)
  CE_A(K0,K1)  CE_D(K2,K3)  CE_A(K4,K5)  CE_D(K6,K7)
  CE_A(K8,K9)  CE_D(K10,K11) CE_A(K12,K13) CE_D(K14,K15)
  CE_A(K0,K2)  CE_A(K1,K3)  CE_D(K4,K6)  CE_D(K5,K7)
  CE_A(K8,K10) CE_A(K9,K11) CE_D(K12,K14) CE_D(K13,K15)
  CE_A(K0,K1)  CE_A(K2,K3)  CE_D(K4,K5)  CE_D(K6,K7)
  CE_A(K8,K9)  CE_A(K10,K11) CE_D(K12,K13) CE_D(K14,K15)
  CE_A(K0,K4)  CE_A(K1,K5)  CE_A(K2,K6)  CE_A(K3,K7)
  CE_D(K8,K12) CE_D(K9,K13) CE_D(K10,K14) CE_D(K11,K15)
  CE_A(K0,K2)  CE_A(K1,K3)  CE_A(K4,K6)  CE_A(K5,K7)
  CE_D(K8,K10) CE_D(K9,K11) CE_D(K12,K14) CE_D(K13,K15)
  CE_A(K0,K1)  CE_A(K2,K3)  CE_A(K4,K5)  CE_A(K6,K7)
  CE_D(K8,K9)  CE_D(K10,K11) CE_D(K12,K13) CE_D(K14,K15)
  CE_A(K0,K8)  CE_A(K1,K9)  CE_A(K2,K10) CE_A(K3,K11)
  CE_A(K4,K12) CE_A(K5,K13) CE_A(K6,K14) CE_A(K7,K15)
  CE_A(K0,K4)  CE_A(K1,K5)  CE_A(K2,K6)  CE_A(K3,K7)
  CE_A(K8,K12) CE_A(K9,K13) CE_A(K10,K14) CE_A(K11,K15)
  CE_A(K0,K2)  CE_A(K1,K3)  CE_A(K4,K6)  CE_A(K5,K7)
  CE_A(K8,K10) CE_A(K9,K11) CE_A(K12,K14) CE_A(K13,K15)
  CE_A(K0,K1)  CE_A(K2,K3)  CE_A(K4,K5)  CE_A(K6,K7)
  CE_A(K8,K9)  CE_A(K10,K11) CE_A(K12,K13) CE_A(K14,K15)

  u64 out16 = ~0ULL;
  TOURNEY16(out16, lane)

  float B = __uint_as_float((unsigned)(__shfl(out16, KNN-1, 64) >> 32));
  const float thr = B*B + 2e-4f;

  const int qr = min(start + RW*32, NND);
  const int ql = max(start - RW*32, 0);
  bool ok;
  {
    bool rok = (qr >= NND);
    if (!rok){
      float xR = sxyid[qr-1].x;
      float dxr = ((float)bucketof(xR)*BW - 8.0f) - xi;
      rok = (dxr > 0.0f) && (dxr*dxr > thr);
    }
    bool lok = (ql <= 0);
    if (!lok){
      float xL = sxyid[ql].x;
      float dxl = xi - ((float)(bucketof(xL)+1)*BW - 8.0f);
      lok = (dxl > 0.0f) && (dxl*dxl > thr);
    }
    ok = rok && lok;
  }
  if (lane == 0 && !ok){
    int s = atomicAdd(ocnt, 1);
    olist[s] = n;
    othr[s] = thr;
  }

  write_outputs(out16, lane, n, idx_out, w_out);
}

// ---------------- bounded rescan for deferred nodes ----------------
// r29-proven ladder+tournament; r35: packed float4 candidate loads.
__global__ __launch_bounds__(256, 4) void knn_ext_r35(
    const float4* __restrict__ sxyid,
    const float* __restrict__ cents, const int* __restrict__ offs,
    const int* __restrict__ olist, const float* __restrict__ othr,
    const int* __restrict__ ocnt,
    int* __restrict__ idx_out, float* __restrict__ w_out)
{
  __shared__ u64 merged[64];         // 4 waves x 16 survivors
  const int lane = threadIdx.x & 63, wv = threadIdx.x >> 6;
  const int cnt = *ocnt;

  for (int slot = blockIdx.x; slot < cnt; slot += gridDim.x){
    const int n = olist[slot];
    const float thr = othr[slot];
    const float rB = __fsqrt_rn(thr) * (1.0f + 2e-6f);
    const float xi = cents[2*n];
    const float yi = cents[2*n+1];
    float sx = xi*xi; FPBAR(sx);
    float sy = yi*yi; FPBAR(sy);
    float sqi = sx + sy; FPBAR(sqi);

    const int bL = bucketof(xi - rB);
    const int bR = bucketof(xi + rB);
    const int posL = offs[bL];
    const int posR = (bR + 1 < NB) ? offs[bR + 1] : NND;

    u64 L[KNN];
    #pragma unroll
    for (int t=0;t<KNN;t++) L[t] = ~0ULL;

    int p = posL + (wv<<6) + lane;
    for (; p + 256 < posR; p += 512){
      float4 c0 = sxyid[p];
      float4 c1 = sxyid[p+256];
      u64 k0 = make_key(xi, yi, sqi, c0.x, c0.y, __float_as_int(c0.z), n);
      u64 k1 = make_key(xi, yi, sqi, c1.x, c1.y, __float_as_int(c1.z), n);
      if (k0 < L[KNN-1]) ladder_insert(L, k0);   // exact: key>=L[15] is a no-op
      if (k1 < L[KNN-1]) ladder_insert(L, k1);
    }
    if (p < posR){
      float4 c0 = sxyid[p];
      u64 k0 = make_key(xi, yi, sqi, c0.x, c0.y, __float_as_int(c0.z), n);
      if (k0 < L[KNN-1]) ladder_insert(L, k0);
    }

    // copy to named scalars (static) -> spill-proof tournament
    u64 K0=L[0], K1=L[1], K2=L[2],  K3=L[3],  K4=L[4],  K5=L[5],  K6=L[6],  K7=L[7],
        K8=L[8], K9=L[9], K10=L[10],K11=L[11],K12=L[12],K13=L[13],K14=L[14],K15=L[15];
    u64 w16 = ~0ULL;
    TOURNEY16(w16, lane)

    if (lane < KNN) merged[(wv<<4) + lane] = w16;
    __syncthreads();
    if (wv == 0){
      u64 out16 = merge64(merged, lane);
      write_outputs(out16, lane, n, idx_out, w_out);
    }
    __syncthreads();   // merged[] reused next slot
  }
}

// ---------------- GEMM: W-in-LDS (depth-2 prefetch) + A-in-registers ----------------
// r30-proven. Used for the two DUAL sage GEMMs.
template<int OUT, bool DUAL, bool BIAS, bool SPLITOUT>
__global__ __launch_bounds__(256, 4) void mm_mfma_r35(
    const unsigned short* __restrict__ A1h, const unsigned short* __restrict__ A1l,
    const unsigned short* __restrict__ A2h, const unsigned short* __restrict__ A2l,
    const unsigned short* __restrict__ W1h, const unsigned short* __restrict__ W1l,
    const unsigned short* __restrict__ W2h, const unsigned short* __restrict__ W2l,
    const float* __restrict__ bias,
    float* __restrict__ Cf, unsigned short* __restrict__ Ch, unsigned short* __restrict__ Cl)
{
  constexpr int NTILW = DUAL ? 4 : 2;      // W tiles per k-step
  constexpr int NW  = DUAL ? 4 : 2;        // W gload_lds per wave per step
  constexpr int NA  = DUAL ? 4 : 2;        // A register loads per lane per step
  constexpr int NCG = OUT / 64;            // 4 or 2
  constexpr int LG  = (NCG == 4) ? 2 : 1;
  constexpr int RTM = (NND + 63) / 64;     // 188
  __shared__ unsigned short sbW[3][NTILW][2048];   // 3 buffers x W tiles x 4KB
  const int lane = threadIdx.x & 63, wv = threadIdx.x >> 6;
  const int bid = blockIdx.x;
  const int xcd = bid & 7;
  const int cg  = (bid >> 3) & (NCG - 1);
  const int rt  = ((bid >> (3 + LG)) << 3) + xcd;
  if (rt >= RTM) return;
  const int row0 = rt*64;
  const int n0 = cg*64;
  const int l15 = lane & 15;
  const int quad = lane >> 4;

  const size_t woff = (size_t)(n0 + lane) * DM;
  const unsigned short* wsrc;
  int wtile, q0;
  if (DUAL){
    wsrc = ((wv==0) ? W1h : (wv==1) ? W1l : (wv==2) ? W2h : W2l) + woff;
    wtile = wv; q0 = 0;
  } else {
    wsrc = ((wv < 2) ? W1h : W1l) + woff;
    wtile = wv >> 1; q0 = (wv & 1) * 2;
  }

  const int am = min(row0 + wv*16 + l15, NND-1);
  const size_t abase = (size_t)am*DM + quad*8;

  f4_t acc[4];
  #pragma unroll
  for (int t=0;t<4;t++) acc[t] = (f4_t){0.f,0.f,0.f,0.f};

  bf8_t A1H[3], A1L[3], A2H[3], A2L[3];

  auto STAGE = [&](int b, int ks){
    if (DUAL){
      #pragma unroll
      for (int j=0;j<4;j++)
        gload16(wsrc + ks*32 + j*8, &sbW[b][wtile][j*512]);
    } else {
      #pragma unroll
      for (int j=0;j<2;j++)
        gload16(wsrc + ks*32 + (q0+j)*8, &sbW[b][wtile][(q0+j)*512]);
    }
  };
  auto LOADA = [&](int s, int ks){
    A1H[s] = *(const bf8_t*)(A1h + abase + ks*32);
    A1L[s] = *(const bf8_t*)(A1l + abase + ks*32);
    if (DUAL){
      A2H[s] = *(const bf8_t*)(A2h + abase + ks*32);
      A2L[s] = *(const bf8_t*)(A2l + abase + ks*32);
    }
  };

  STAGE(0, 0); LOADA(0, 0);
  STAGE(1, 1); LOADA(1, 1);
  constexpr int NKS = DM/32;             // 8
  #pragma unroll
  for (int ks=0; ks<NKS; ++ks){
    const int b = ks % 3;
    if (ks + 2 < NKS){ STAGE((ks+2)%3, ks+2); LOADA((ks+2)%3, ks+2); }
    if (ks + 2 < NKS)      asm volatile("s_waitcnt vmcnt(%0)" :: "i"(2*(NW+NA)) : "memory");
    else if (ks + 1 < NKS) asm volatile("s_waitcnt vmcnt(%0)" :: "i"(NW+NA) : "memory");
    else                   asm volatile("s_waitcnt vmcnt(0)" ::: "memory");
    __builtin_amdgcn_sched_barrier(0);
    __builtin_amdgcn_s_barrier();        // all waves: W tiles for ks complete
    __builtin_amdgcn_sched_barrier(0);
    {
      bf8_t a1h = A1H[b], a1l = A1L[b];
      bf8_t a2h, a2l;
      if (DUAL){ a2h = A2H[b]; a2l = A2L[b]; }
      #pragma unroll
      for (int t=0;t<4;t++){
        const int wr = quad*512 + (t*16 + l15)*8;
        bf8_t bh = *(const bf8_t*)&sbW[b][0][wr];
        bf8_t bl = *(const bf8_t*)&sbW[b][1][wr];
        acc[t] = __builtin_amdgcn_mfma_f32_16x16x32_bf16(a1h, bh, acc[t], 0, 0, 0);
        acc[t] = __builtin_amdgcn_mfma_f32_16x16x32_bf16(a1h, bl, acc[t], 0, 0, 0);
        acc[t] = __builtin_amdgcn_mfma_f32_16x16x32_bf16(a1l, bh, acc[t], 0, 0, 0);
        if (DUAL){
          bf8_t ch = *(const bf8_t*)&sbW[b][2][wr];
          bf8_t cl = *(const bf8_t*)&sbW[b][3][wr];
          acc[t] = __builtin_amdgcn_mfma_f32_16x16x32_bf16(a2h, ch, acc[t], 0, 0, 0);
          acc[t] = __builtin_amdgcn_mfma_f32_16x16x32_bf16(a2h, cl, acc[t], 0, 0, 0);
          acc[t] = __builtin_amdgcn_mfma_f32_16x16x32_bf16(a2l, ch, acc[t], 0, 0, 0);
        }
      }
    }
    __builtin_amdgcn_sched_barrier(0);
    asm volatile("s_waitcnt lgkmcnt(0)" ::: "memory");
    __builtin_amdgcn_s_barrier();        // all waves done reading buffer b
    __builtin_amdgcn_sched_barrier(0);
  }

  #pragma unroll
  for (int t=0;t<4;t++){
    int n = n0 + t*16 + l15;
    float bv = BIAS ? bias[n] : 0.f;
    #pragma unroll
    for (int r=0;r<4;r++){
      int row = row0 + wv*16 + quad*4 + r;
      if (row < NND){
        float v = geluf(acc[t][r] + bv);
        if (SPLITOUT){
          unsigned short hb = bf16_rne(v);
          float hf = __uint_as_float(((unsigned)hb) << 16);
          Ch[(size_t)row*OUT + n] = hb;
          Cl[(size_t)row*OUT + n] = bf16_rne(v - hf);
        } else {
          Cf[(size_t)row*OUT + n] = v;
        }
      }
    }
  }
}

// ---------------- CLASSIFIER: full-row GEMM + fused cls2 dot ----------------
// r35: one block = 64 rows x ALL 128 cols (NCG=1); wave = 16 rows x 128 cols
// (8 MFMA tiles). Same r30 pipeline (W-LDS 3-buffer depth-2, A-in-reg).
// Epilogue: gelu -> in-register dot with w2 (each lane covers cols == l15
// mod 16) -> 16-lane xor-reduce (a row lives entirely in one quad-group) ->
// sigmoid -> write d_out. Deletes cls2 dispatch + the 12MB hid round-trip.
// Dot sum ORDER differs from the old 64-lane tree (perturbation ~1e-7 rel,
// << bf16 output quantum).
__global__ __launch_bounds__(256, 4) void cls_fused_r35(
    const unsigned short* __restrict__ A1h, const unsigned short* __restrict__ A1l,
    const unsigned short* __restrict__ W1h, const unsigned short* __restrict__ W1l,
    const float* __restrict__ bias, const float* __restrict__ w2,
    const float* __restrict__ b2,
    void* __restrict__ out, const int* __restrict__ flag)
{
  constexpr int NW = 4, NA = 2;            // vm ops per wave per step
  constexpr int RTM = (NND + 63) / 64;     // 188
  __shared__ unsigned short sbW[3][2][4096];   // 3 buf x {h,l} x 8KB (48KB)
  const int lane = threadIdx.x & 63, wv = threadIdx.x >> 6;
  const int bid = blockIdx.x;
  const int xcd = bid & 7;
  const int rt  = ((bid >> 3) << 3) + xcd;
  if (rt >= RTM) return;
  const int row0 = rt*64;
  const int l15 = lane & 15;
  const int quad = lane >> 4;

  const int am = min(row0 + wv*16 + l15, NND-1);
  const size_t abase = (size_t)am*DM + quad*8;

  f4_t acc[8];
  #pragma unroll
  for (int t=0;t<8;t++) acc[t] = (f4_t){0.f,0.f,0.f,0.f};

  bf8_t A1H[3], A1L[3];

  // staging: 16 chunks/step; wave wv does g = wv*4..wv*4+3.
  // g: a=g>>3 (h/l), rem=g&7, q=rem>>1, half=rem&1 (cols half*64..+63).
  // tile layout [q=4][col=128][16B]: ushort offset = q*1024 + col*8.
  auto STAGE = [&](int b, int ks){
    #pragma unroll
    for (int j=0;j<4;j++){
      const int g = wv*4 + j;
      const int a = g >> 3, rem = g & 7, q = rem >> 1, half = rem & 1;
      const unsigned short* ws = (a ? W1l : W1h)
          + (size_t)(half*64 + lane)*DM + ks*32 + q*8;
      gload16(ws, &sbW[b][a][q*1024 + half*512]);
    }
  };
  auto LOADA = [&](int s, int ks){
    A1H[s] = *(const bf8_t*)(A1h + abase + ks*32);
    A1L[s] = *(const bf8_t*)(A1l + abase + ks*32);
  };

  STAGE(0, 0); LOADA(0, 0);
  STAGE(1, 1); LOADA(1, 1);
  constexpr int NKS = DM/32;             // 8
  #pragma unroll
  for (int ks=0; ks<NKS; ++ks){
    const int b = ks % 3;
    if (ks + 2 < NKS){ STAGE((ks+2)%3, ks+2); LOADA((ks+2)%3, ks+2); }
    if (ks + 2 < NKS)      asm volatile("s_waitcnt vmcnt(%0)" :: "i"(2*(NW+NA)) : "memory");
    else if (ks + 1 < NKS) asm volatile("s_waitcnt vmcnt(%0)" :: "i"(NW+NA) : "memory");
    else                   asm volatile("s_waitcnt vmcnt(0)" ::: "memory");
    __builtin_amdgcn_sched_barrier(0);
    __builtin_amdgcn_s_barrier();
    __builtin_amdgcn_sched_barrier(0);
    {
      bf8_t a1h = A1H[b], a1l = A1L[b];
      #pragma unroll
      for (int t=0;t<8;t++){
        const int wr = quad*1024 + (t*16 + l15)*8;
        bf8_t bh = *(const bf8_t*)&sbW[b][0][wr];
        bf8_t bl = *(const bf8_t*)&sbW[b][1][wr];
        acc[t] = __builtin_amdgcn_mfma_f32_16x16x32_bf16(a1h, bh, acc[t], 0, 0, 0);
        acc[t] = __builtin_amdgcn_mfma_f32_16x16x32_bf16(a1h, bl, acc[t], 0, 0, 0);
        acc[t] = __builtin_amdgcn_mfma_f32_16x16x32_bf16(a1l, bh, acc[t], 0, 0, 0);
      }
    }
    __builtin_amdgcn_sched_barrier(0);
    asm volatile("s_waitcnt lgkmcnt(0)" ::: "memory");
    __builtin_amdgcn_s_barrier();
    __builtin_amdgcn_sched_barrier(0);
  }

  // epilogue: gelu + dot(w2) + 16-lane reduce + sigmoid -> out
  const int is_bf16 = *flag;
  float partial0=0.f, partial1=0.f, partial2=0.f, partial3=0.f;
  #pragma unroll
  for (int t=0;t<8;t++){
    const int c = t*16 + l15;
    const float bv = bias[c];
    const float wc = w2[c];
    partial0 = fmaf(geluf(acc[t][0] + bv), wc, partial0);
    partial1 = fmaf(geluf(acc[t][1] + bv), wc, partial1);
    partial2 = fmaf(geluf(acc[t][2] + bv), wc, partial2);
    partial3 = fmaf(geluf(acc[t][3] + bv), wc, partial3);
  }
  #pragma unroll
  for (int o=1; o<16; o<<=1){
    partial0 += __shfl_xor(partial0, o, 64);
    partial1 += __shfl_xor(partial1, o, 64);
    partial2 += __shfl_xor(partial2, o, 64);
    partial3 += __shfl_xor(partial3, o, 64);
  }
  if (l15 == 0){
    const float bb = b2[0];
    float pr[1];
    #pragma unroll
    for (int r=0;r<4;r++){
      float s = (r==0)?partial0:(r==1)?partial1:(r==2)?partial2:partial3;
      int row = row0 + wv*16 + quad*4 + r;
      if (row < NND){
        float v = 1.0f / (1.0f + expf(-(s + bb)));
        if (is_bf16) ((__hip_bfloat16*)out)[row] = __float2bfloat16(v);
        else         ((float*)out)[row] = v;
      }
      (void)pr;
    }
  }
}

// ---------------- weighted neighbor aggregation ----------------
__global__ __launch_bounds__(256) void agg_kernel_r35(
    const unsigned short* __restrict__ hh, const unsigned short* __restrict__ hl,
    const int* __restrict__ idx, const float* __restrict__ w,
    unsigned short* __restrict__ oh, unsigned short* __restrict__ ol)
{
  const int lane = threadIdx.x & 63, wid = threadIdx.x >> 6;
  const int n = blockIdx.x*4 + wid;
  const int base = n*KNN;
  const int c = lane*4;
  float4 acc = make_float4(0.f,0.f,0.f,0.f);
  for (int k=0;k<KNN;k++){
    int j = idx[base+k];
    float wk = w[base+k];
    ushort4 vh = *(const ushort4*)(hh + (size_t)j*DM + c);
    ushort4 vl = *(const ushort4*)(hl + (size_t)j*DM + c);
    acc.x = fmaf(wk, bfpair(vh.x, vl.x), acc.x);
    acc.y = fmaf(wk, bfpair(vh.y, vl.y), acc.y);
    acc.z = fmaf(wk, bfpair(vh.z, vl.z), acc.z);
    acc.w = fmaf(wk, bfpair(vh.w, vl.w), acc.w);
  }
  unsigned short h0 = bf16_rne(acc.x); float f0 = __uint_as_float(((unsigned)h0) << 16);
  unsigned short h1 = bf16_rne(acc.y); float f1 = __uint_as_float(((unsigned)h1) << 16);
  unsigned short h2 = bf16_rne(acc.z); float f2 = __uint_as_float(((unsigned)h2) << 16);
  unsigned short h3 = bf16_rne(acc.w); float f3 = __uint_as_float(((unsigned)h3) << 16);
  ushort4 sh = make_ushort4(h0, h1, h2, h3);
  ushort4 sl = make_ushort4(bf16_rne(acc.x - f0), bf16_rne(acc.y - f1),
                            bf16_rne(acc.z - f2), bf16_rne(acc.w - f3));
  *(ushort4*)(oh + (size_t)n*DM + c) = sh;
  *(ushort4*)(ol + (size_t)n*DM + c) = sl;
}

// ---------------- h = h + layernorm(tmp)*g + b  (h stored as bf16 hi/lo) ----------------
__global__ __launch_bounds__(256) void ln_res_kernel_r35(
    unsigned short* __restrict__ hh, unsigned short* __restrict__ hl,
    const float* __restrict__ tmp, const float* __restrict__ g, const float* __restrict__ b)
{
  const int lane = threadIdx.x & 63, wid = threadIdx.x >> 6;
  const int n = blockIdx.x*4 + wid;
  float4 x = *(const float4*)(tmp + (size_t)n*DM + lane*4);
  float s = (x.x + x.y) + (x.z + x.w);
  #pragma unroll
  for (int off=32; off>0; off>>=1) s += __shfl_xor(s, off, 64);
  float mu = s * (1.0f/DM);
  float dx0 = x.x-mu, dx1 = x.y-mu, dx2 = x.z-mu, dx3 = x.w-mu;
  float v = (dx0*dx0 + dx1*dx1) + (dx2*dx2 + dx3*dx3);
  #pragma unroll
  for (int off=32; off>0; off>>=1) v += __shfl_xor(v, off, 64);
  float rs = 1.0f / sqrtf(v * (1.0f/DM) + 1e-5f);
  int c = lane*4;
  float4 gv = *(const float4*)(g + c);
  float4 bv = *(const float4*)(b + c);
  ushort4 vh = *(const ushort4*)(hh + (size_t)n*DM + c);
  ushort4 vl = *(const ushort4*)(hl + (size_t)n*DM + c);
  float o0 = bfpair(vh.x, vl.x) + dx0*rs*gv.x + bv.x;
  float o1 = bfpair(vh.y, vl.y) + dx1*rs*gv.y + bv.y;
  float o2 = bfpair(vh.z, vl.z) + dx2*rs*gv.z + bv.z;
  float o3 = bfpair(vh.w, vl.w) + dx3*rs*gv.w + bv.w;
  unsigned short h0 = bf16_rne(o0); float f0 = __uint_as_float(((unsigned)h0) << 16);
  unsigned short h1 = bf16_rne(o1); float f1 = __uint_as_float(((unsigned)h1) << 16);
  unsigned short h2 = bf16_rne(o2); float f2 = __uint_as_float(((unsigned)h2) << 16);
  unsigned short h3 = bf16_rne(o3); float f3 = __uint_as_float(((unsigned)h3) << 16);
  *(ushort4*)(hh + (size_t)n*DM + c) = make_ushort4(h0, h1, h2, h3);
  *(ushort4*)(hl + (size_t)n*DM + c) = make_ushort4(bf16_rne(o0 - f0), bf16_rne(o1 - f1),
                                                    bf16_rne(o2 - f2), bf16_rne(o3 - f3));
}

extern "C" void kernel_launch(void* const* d_in, const int* in_sizes, int n_in,
                              void* d_out, int out_size, void* d_ws, size_t ws_size,
                              hipStream_t stream)
{
  // ---- workspace layout (~46.6 MB), fully rewritten every call ----
  char* base = (char*)d_ws;
  int*   flag = (int*)base;                                   // 16 B slot
  float* wreg = (float*)(base + 16);
  static const int sizes[16] = {
    NND*256, NND*2, 256*256, 256, 256*256, 256*256, 256, 256,
    256*256, 256*256, 256, 256, 128*256, 128, 128, 1
  };
  float* ptrs[16];
  {
    float* p = wreg;
    for (int i = 2; i < 16; i++){ ptrs[i] = p; p += (sizes[i] + 3) & ~3; }
    ptrs[1] = p;                          // cents  [24,000]
    p += NND*2;
    ptrs[0] = p;                          // feats region  [3,072,000 floats]
  }
  float* F    = ptrs[0];                  // f32 tmp view of feats region
  unsigned short* fh = (unsigned short*)ptrs[0];          // feats hi
  unsigned short* fl = fh + (size_t)NND*DM;               // feats lo
  float* C    = ptrs[1];
  float* hbase = F + (size_t)NND*DM;
  unsigned short* h_hi = (unsigned short*)hbase;
  unsigned short* h_lo = h_hi + (size_t)NND*DM;
  float* abase = hbase + (size_t)NND*DM;
  unsigned short* a_hi = (unsigned short*)abase;
  unsigned short* a_lo = a_hi + (size_t)NND*DM;
  float* hid  = abase + (size_t)NND*DM;   // (region retained; cls2 fused away)
  int*  gidx  = (int*)(hid + (size_t)NND*128);
  float* gw   = (float*)(gidx + (size_t)NND*KNN);
  // knn pre-pass scratch (r35: packed float4 candidates)
  float4* sxyid = (float4*)(gw + (size_t)NND*KNN);
  int*    hist  = (int*)(sxyid + NND);
  int*    cursor= hist + NB;
  int*    offs  = cursor + NB;
  int*    ocnt  = offs + NB;
  int*    olist = ocnt + 4;               // 16B pad keeps wh 16B-aligned
  float*  othr  = (float*)(olist + NND);  // thr per deferred node
  // bf16 hi/lo weights (enc_w | g1_ws | g1_wn | g2_ws | g2_wn | cls_w1), 16B-aligned
  unsigned short* wh = (unsigned short*)(((uintptr_t)(othr + NND) + 15) & ~(uintptr_t)15);
  unsigned short* wl = wh + NWELEM;

  // ---- dtype detect + decode (weights split to hi/lo IN decode; r34-proven) ----
  detect_kernel_r35<<<1, 256, 0, stream>>>((const unsigned*)d_in[1], 4096,
                                           (const unsigned*)d_in[0], 16384, flag);
  SegTable t;
  int total = 0;
  for (int i = 0; i < 16; i++){
    t.src[i] = d_in[i];
    t.dst[i] = ptrs[i];
    t.cnt[i] = sizes[i];
    t.wofs[i] = -1;
    total += sizes[i];
  }
  t.dst[0] = nullptr;       // feats handled via fh/fl
  t.wofs[2]  = 0;           // enc_w
  t.wofs[4]  = 65536;       // g1_ws
  t.wofs[5]  = 131072;      // g1_wn
  t.wofs[8]  = 196608;      // g2_ws
  t.wofs[9]  = 262144;      // g2_wn
  t.wofs[12] = 327680;      // cls_w1
  t.total = total;
  decode_kernel_r35<<<(total + 255)/256, 256, 0, stream>>>(t, fh, fl, wh, wl, flag);

  const float* enc_b  = ptrs[3];
  const float* g1_g   = ptrs[6];  const float* g1_b   = ptrs[7];
  const float* g2_g   = ptrs[10]; const float* g2_b   = ptrs[11];
  const float* cls_b1 = ptrs[13];
  const float* cls_w2 = ptrs[14]; const float* cls_b2 = ptrs[15];

  dim3 b256(256);
  // knn pre-pass: bucket counting sort by x (+ zero outlier counter)
  zero_kernel_r35<<<(NB + 255)/256, b256, 0, stream>>>(hist, cursor, ocnt);
  count_kernel_r35<<<(NND + 255)/256, b256, 0, stream>>>(C, hist);
  scan_kernel_r35<<<1, 1024, 0, stream>>>(hist, offs);
  scatter_kernel_r35<<<(NND + 255)/256, b256, 0, stream>>>(C, offs, cursor, sxyid);
  // swizzled grids: 24 rt-groups of 8 XCD-slots x NCG col-groups
  const int G4 = 24 * 8 * 4;   // 768  (OUT=256)
  // FUSED: knn_fixed (blocks 0..2999) || encoder GEMM (blocks 3000..3767)
  fused_enc_knn_r35<<<KBLK + G4, b256, 0, stream>>>(
      fh, fl, wh + 0, wl + 0, enc_b, h_hi, h_lo,
      sxyid, C, offs, gidx, gw, ocnt, olist, othr);
  knn_ext_r35<<<2048, b256, 0, stream>>>(sxyid, C, offs, olist, othr, ocnt, gidx, gw);
  // sage layer 1 (tmp := F region, feats dead after encoder)
  agg_kernel_r35<<<NND/4, b256, 0, stream>>>(h_hi, h_lo, gidx, gw, a_hi, a_lo);
  mm_mfma_r35<256,true,false,false><<<G4, b256, 0, stream>>>(h_hi, h_lo, a_hi, a_lo,
      wh + 65536, wl + 65536, wh + 131072, wl + 131072, nullptr, F, nullptr, nullptr);
  ln_res_kernel_r35<<<NND/4, b256, 0, stream>>>(h_hi, h_lo, F, g1_g, g1_b);
  // sage layer 2
  agg_kernel_r35<<<NND/4, b256, 0, stream>>>(h_hi, h_lo, gidx, gw, a_hi, a_lo);
  mm_mfma_r35<256,true,false,false><<<G4, b256, 0, stream>>>(h_hi, h_lo, a_hi, a_lo,
      wh + 196608, wl + 196608, wh + 262144, wl + 262144, nullptr, F, nullptr, nullptr);
  ln_res_kernel_r35<<<NND/4, b256, 0, stream>>>(h_hi, h_lo, F, g2_g, g2_b);
  // classifier: full-row GEMM + fused cls2 dot -> d_out (192 blocks)
  cls_fused_r35<<<24*8, b256, 0, stream>>>(h_hi, h_lo,
      wh + 327680, wl + 327680, cls_b1, cls_w2, cls_b2, d_out, flag);
}

// Round 19
// 374.557 us; speedup vs baseline: 1.0045x; 1.0045x over previous
//
#include <hip/hip_runtime.h>
#include <hip/hip_bf16.h>
#include <stdint.h>

#define NND 12000
#define DM  256
#define KNN 16
#define NB  4096          // x-buckets
#define BW  0.00390625f   // bucket width = 1/256 over [-8, 8)
#define RW  16            // fixed-window rounds (16*64 = 1024 candidates)
#define NWELEM 360448     // total weight elements converted to bf16 hi/lo
#define KBLK (NND/4)      // 3000 knn blocks first (r32 ordering, measured best)

// Opaque register barrier: prevents FMA contraction (r9: made knn bit-match numpy
// -> absmax 0.0. DO NOT REMOVE from knn path).
#define FPBAR(x) asm volatile("" : "+v"(x))

typedef unsigned long long u64;
typedef __attribute__((ext_vector_type(8))) short bf8_t;   // 8 bf16 (4 VGPRs)
typedef __attribute__((ext_vector_type(4))) float f4_t;

__device__ __forceinline__ float geluf(float x){ return 0.5f*x*(1.0f + erff(x*0.70710678118654752f)); }
__device__ __forceinline__ int bucketof(float x){
  int b = (int)floorf((x + 8.0f) * 256.0f);
  return min(max(b, 0), NB-1);
}

__device__ __forceinline__ unsigned short bf16_rne(float x){
  unsigned u = __float_as_uint(x);
  unsigned r = u + 0x7FFF + ((u >> 16) & 1);
  return (unsigned short)(r >> 16);
}

__device__ __forceinline__ float bfpair(unsigned short h, unsigned short l){
  return __uint_as_float(((unsigned)h) << 16) + __uint_as_float(((unsigned)l) << 16);
}

// async global->LDS, 16B per lane. LDS dest is WAVE-UNIFORM base + lane*16;
// global src is per-lane. Completion tracked by vmcnt.
__device__ __forceinline__ void gload16(const unsigned short* g, unsigned short* l){
  __builtin_amdgcn_global_load_lds(
      (__attribute__((address_space(1))) void*)g,
      (__attribute__((address_space(3))) void*)l, 16, 0, 0);
}

// bit-exact numpy distance key (r9-verified). Low 32 bits = original node idx.
__device__ __forceinline__ u64 make_key(float xi, float yi, float sqi,
                                        float cx, float cy, int jd, int self){
  float ax = cx*cx;  FPBAR(ax);
  float ay = cy*cy;  FPBAR(ay);
  float sqj = ax + ay;   FPBAR(sqj);
  float px = xi*cx;    FPBAR(px);
  float py = yi*cy;    FPBAR(py);
  float dt = px + py;    FPBAR(dt);            // NO-FMA dot
  float two_dt = 2.0f*dt;  FPBAR(two_dt);
  float ss = sqi + sqj;    FPBAR(ss);
  float d2 = ss - two_dt;  FPBAR(d2);
  float dist = __fsqrt_rn(fmaxf(d2, 0.0f));
  u64 key = ((u64)__float_as_uint(dist) << 32) | (unsigned)jd;
  return (jd == self) ? ~0ULL : key;
}

__device__ __forceinline__ void ladder_insert(u64* L, u64 key){
  bool c[KNN];
  #pragma unroll
  for (int t=0;t<KNN;t++) c[t] = key < L[t];
  #pragma unroll
  for (int t=KNN-1;t>=1;t--) L[t] = c[t-1] ? L[t-1] : (c[t] ? key : L[t]);
  L[0] = c[0] ? key : L[0];
}

// merge 64 candidate keys (one per lane) -> lane r holds r-th smallest (r<16).
__device__ __forceinline__ u64 merge64(const u64* m, int lane)
{
  u64 cur = m[lane];
  u64 out16 = ~0ULL;
  for (int r=0;r<KNN;r++){
    u64 k = cur; int who = lane;
    #pragma unroll
    for (int o=32;o>0;o>>=1){
      u64 ok = __shfl_xor(k, o, 64);
      int ow = __shfl_xor(who, o, 64);
      if (ok < k){ k = ok; who = ow; }
    }
    if (lane == r) out16 = k;
    if (lane == who) cur = ~0ULL;
  }
  return out16;
}

__device__ __forceinline__ void write_outputs(u64 out16, int lane, int n,
    int* __restrict__ idx_out, float* __restrict__ w_out)
{
  if (lane < KNN) idx_out[(size_t)n*KNN + lane] = (int)(unsigned)(out16 & 0xFFFFFFFFull);
  u64 kt[KNN];
  #pragma unroll
  for (int t=0;t<KNN;t++) kt[t] = __shfl(out16, t, 64);
  float inv[KNN];
  #pragma unroll
  for (int t=0;t<KNN;t++){
    float d = __uint_as_float((unsigned)(kt[t] >> 32));
    inv[t] = __fdiv_rn(1.0f, fmaxf(d, 1e-4f));
  }
  float r8v[8];
  #pragma unroll
  for (int t=0;t<8;t++){ r8v[t] = inv[t] + inv[t+8]; FPBAR(r8v[t]); }
  float s01 = r8v[0]+r8v[1]; FPBAR(s01);
  float s23 = r8v[2]+r8v[3]; FPBAR(s23);
  float s45 = r8v[4]+r8v[5]; FPBAR(s45);
  float s67 = r8v[6]+r8v[7]; FPBAR(s67);
  float sA = s01+s23; FPBAR(sA);
  float sB = s45+s67; FPBAR(sB);
  float s = sA + sB;
  s = fmaxf(s, 1e-8f);
  if (lane < KNN){
    float d = __uint_as_float((unsigned)(out16 >> 32));
    float invL = __fdiv_rn(1.0f, fmaxf(d, 1e-4f));
    w_out[(size_t)n*KNN + lane] = __fdiv_rn(invL, s);
  }
}

// compare-exchange macros for the bitonic network (named scalars only —
// r20/r28 lesson: u64 ARRAYS mutated through pointers/under exec-mask get
// lowered to scratch (VGPR 28/32 signatures). Named scalars stay in regs.
#define CE_A(x,y) { u64 mn_=(x)<(y)?(x):(y); u64 mx_=(x)<(y)?(y):(x); (x)=mn_; (y)=mx_; }
#define CE_D(x,y) { u64 mn_=(x)<(y)?(x):(y); u64 mx_=(x)<(y)?(y):(x); (x)=mx_; (y)=mn_; }

// r36: EXACT wave-min of 64 head keys via 32-bit DISTANCE-PROXY butterfly.
// Key = (dist_bits<<32)|idx with positive-float dist -> min dist found with a
// u32 v_min butterfly (half the u64 cost). If exactly one head matches
// (always, for random data) that head IS the u64 min; on ties (wave-uniform
// rare branch) fall back to the exact full-u64 butterfly. Bit-exact:
// unique-idx keys => tie path returns min(dist,idx) among tied lanes;
// all-sentinel rounds take the tie path and reproduce the old who=ffs=0.
#define PSELECT(k, who, cur, curd) {                                \
    unsigned d_ = curd;                                             \
    _Pragma("unroll")                                               \
    for (int o_=32;o_>0;o_>>=1){                                    \
      unsigned od_ = __shfl_xor(d_, o_, 64);                        \
      d_ = min(d_, od_);                                            \
    }                                                               \
    u64 ball_ = __ballot(curd == d_);                               \
    if (ball_ & (ball_ - 1)){                                       \
      u64 c2_ = (curd == d_) ? cur : ~0ULL;                         \
      _Pragma("unroll")                                             \
      for (int o_=32;o_>0;o_>>=1){                                  \
        u64 oc_ = __shfl_xor(c2_, o_, 64);                          \
        if (oc_ < c2_) c2_ = oc_;                                   \
      }                                                             \
      k = c2_;                                                      \
      who = __ffsll(__ballot(cur == k)) - 1;                        \
    } else {                                                        \
      who = __ffsll(ball_) - 1;                                     \
      k = __shfl(cur, who, 64);                                     \
    }                                                               \
  }

// proxy tournament over NAMED scalars K0..K15 with register-shift refill
// (knn_ext; r29-proven refill + r36 proxy selection).
#define TOURNEY16(out16, lane) {                                   \
    u64 cur = K0; unsigned curd = (unsigned)(cur >> 32);           \
    for (int r_=0;r_<KNN;r_++){                                    \
      u64 k_; int who_;                                            \
      PSELECT(k_, who_, cur, curd)                                 \
      if ((lane) == r_) out16 = k_;                                \
      if ((lane) == who_){                                         \
        K0=K1; K1=K2; K2=K3; K3=K4; K4=K5; K5=K6; K6=K7; K7=K8;    \
        K8=K9; K9=K10; K10=K11; K11=K12; K12=K13; K13=K14;         \
        K14=K15; K15=~0ULL;                                        \
        cur = K0; curd = (unsigned)(cur >> 32);                    \
      }                                                            \
    }                                                              \
  }

// ---------------- dtype detection (proven: picks f32 here) ----------------
__global__ __launch_bounds__(256) void detect_kernel_r37(
    const unsigned* __restrict__ a, int na,
    const unsigned* __restrict__ b, int nb, int* __restrict__ flag)
{
  __shared__ int cnt;
  if (threadIdx.x == 0) cnt = 0;
  __syncthreads();
  int c = 0;
  for (int i = threadIdx.x; i < na; i += 256){
    int ex = (a[i] >> 7) & 0xFF;
    c += (ex >= 113 && ex <= 131) ? 1 : 0;
  }
  for (int i = threadIdx.x; i < nb; i += 256){
    int ex = (b[i] >> 7) & 0xFF;
    c += (ex >= 113 && ex <= 131) ? 1 : 0;
  }
  atomicAdd(&cnt, c);
  __syncthreads();
  if (threadIdx.x == 0) *flag = (cnt > (na + nb) / 2) ? 1 : 0;
}

// ---------------- decode all inputs (fused weight hi/lo split; r34-proven) ----------------
struct SegTable {
  const void* src[16];
  float*      dst[16];
  int         cnt[16];
  int         wofs[16];   // >=0: offset into wh/wl for weight segs, else -1
  int         total;
};

__global__ __launch_bounds__(256) void decode_kernel_r37(SegTable t,
    unsigned short* __restrict__ fh, unsigned short* __restrict__ fl,
    unsigned short* __restrict__ dh, unsigned short* __restrict__ dl,
    const int* __restrict__ flag)
{
  const int is_bf16 = *flag;
  for (int e = blockIdx.x*256 + threadIdx.x; e < t.total; e += gridDim.x*256){
    int rem = e, s = 0;
    while (rem >= t.cnt[s]){ rem -= t.cnt[s]; ++s; }
    float v;
    if (is_bf16) v = __uint_as_float(((unsigned)((const unsigned short*)t.src[s])[rem]) << 16);
    else         v = ((const float*)t.src[s])[rem];
    if (s == 0){
      unsigned short hb = bf16_rne(v);
      float hf = __uint_as_float(((unsigned)hb) << 16);
      fh[rem] = hb;
      fl[rem] = bf16_rne(v - hf);
    } else {
      int wo = t.wofs[s];
      if (wo >= 0){
        unsigned short hb = bf16_rne(v);
        float hf = __uint_as_float(((unsigned)hb) << 16);
        dh[wo + rem] = hb;
        dl[wo + rem] = bf16_rne(v - hf);
      } else {
        t.dst[s][rem] = v;
      }
    }
  }
}

// ---------------- bucket pre-pass ----------------
__global__ __launch_bounds__(256) void zero_kernel_r37(int* __restrict__ hist, int* __restrict__ cursor,
                                                       int* __restrict__ ocnt)
{
  int t = blockIdx.x*256 + threadIdx.x;
  if (t < NB){ hist[t] = 0; cursor[t] = 0; }
  if (blockIdx.x == 0 && threadIdx.x == 0) *ocnt = 0;
}

__global__ __launch_bounds__(256) void count_kernel_r37(const float* __restrict__ cents,
                                                        int* __restrict__ hist)
{
  int i = blockIdx.x*256 + threadIdx.x;
  if (i < NND) atomicAdd(&hist[bucketof(cents[2*i])], 1);
}

__global__ __launch_bounds__(1024) void scan_kernel_r37(const int* __restrict__ hist,
                                                        int* __restrict__ offs)
{
  __shared__ int s[1024];
  int t = threadIdx.x;
  int h0 = hist[t*4], h1 = hist[t*4+1], h2 = hist[t*4+2], h3 = hist[t*4+3];
  int tot = h0+h1+h2+h3;
  s[t] = tot;
  __syncthreads();
  for (int d=1; d<1024; d<<=1){
    int v = (t >= d) ? s[t-d] : 0;
    __syncthreads();
    s[t] += v;
    __syncthreads();
  }
  int excl = s[t] - tot;
  offs[t*4]   = excl;
  offs[t*4+1] = excl + h0;
  offs[t*4+2] = excl + h0 + h1;
  offs[t*4+3] = excl + h0 + h1 + h2;
}

// scatter packs (x, y, bitcast(id)) into ONE float4 (r35-proven).
__global__ __launch_bounds__(256) void scatter_kernel_r37(const float* __restrict__ cents,
    const int* __restrict__ offs, int* __restrict__ cursor,
    float4* __restrict__ sxyid)
{
  int i = blockIdx.x*256 + threadIdx.x;
  if (i < NND){
    float x = cents[2*i], y = cents[2*i+1];
    int b = bucketof(x);
    int pos = offs[b] + atomicAdd(&cursor[b], 1);
    sxyid[pos] = make_float4(x, y, __int_as_float(i), 0.f);
  }
}

// ---------------- FUSED: encoder GEMM (blocks >= KBLK) || knn_fixed (blocks < KBLK) ----------------
// r32-proven structure. r36/r37: knn tournament uses PSELECT (32-bit proxy)
// and refills from a per-wave slice of the SAME 24KB LDS the encoder path
// uses (knn blocks never run enc code -> union is free; occupancy unchanged).
// Slots 1..11 in LDS (4 waves x 11 x 64 x 8B = 22528 <= 24576); K12..K15
// stay in registers with a select fallback (reached only after 12+ wins by
// one lane). Selection order identical -> bit-identical outputs.
__global__ __launch_bounds__(256, 4) void fused_enc_knn_r37(
    // encoder args
    const unsigned short* __restrict__ A1h, const unsigned short* __restrict__ A1l,
    const unsigned short* __restrict__ W1h, const unsigned short* __restrict__ W1l,
    const float* __restrict__ bias,
    unsigned short* __restrict__ Ch, unsigned short* __restrict__ Cl,
    // knn args
    const float4* __restrict__ sxyid,
    const float* __restrict__ cents, const int* __restrict__ offs,
    int* __restrict__ idx_out, float* __restrict__ w_out,
    int* __restrict__ ocnt, int* __restrict__ olist, float* __restrict__ othr)
{
  __shared__ union {
    unsigned short enc[3][2][2048];   // 24KB, encoder path
    u64            knn[4][11*64];     // 22528B, knn tournament slices
  } shm;
  const int lane = threadIdx.x & 63, wv = threadIdx.x >> 6;

  if (blockIdx.x >= KBLK){
    // ================= encoder body (mm_mfma_r30 <256,false,true,true>) ===========
    constexpr int NW = 2, NA = 2;
    constexpr int NCG = 4, LG = 2;
    constexpr int RTM = (NND + 63) / 64;   // 188
    const int ebid = blockIdx.x - KBLK;
    const int xcd = ebid & 7;
    const int cg  = (ebid >> 3) & (NCG - 1);
    const int rt  = ((ebid >> (3 + LG)) << 3) + xcd;
    if (rt >= RTM) return;
    const int row0 = rt*64;
    const int n0 = cg*64;
    const int l15 = lane & 15;
    const int quad = lane >> 4;

    const size_t woff = (size_t)(n0 + lane) * DM;
    const unsigned short* wsrc = ((wv < 2) ? W1h : W1l) + woff;
    const int wtile = wv >> 1, q0 = (wv & 1) * 2;

    const int am = min(row0 + wv*16 + l15, NND-1);
    const size_t abase = (size_t)am*DM + quad*8;

    f4_t acc[4];
    #pragma unroll
    for (int t=0;t<4;t++) acc[t] = (f4_t){0.f,0.f,0.f,0.f};

    bf8_t A1H[3], A1L[3];

    auto STAGE = [&](int b, int ks){
      #pragma unroll
      for (int j=0;j<2;j++)
        gload16(wsrc + ks*32 + (q0+j)*8, &shm.enc[b][wtile][(q0+j)*512]);
    };
    auto LOADA = [&](int s, int ks){
      A1H[s] = *(const bf8_t*)(A1h + abase + ks*32);
      A1L[s] = *(const bf8_t*)(A1l + abase + ks*32);
    };

    STAGE(0, 0); LOADA(0, 0);
    STAGE(1, 1); LOADA(1, 1);
    constexpr int NKS = DM/32;             // 8
    #pragma unroll
    for (int ks=0; ks<NKS; ++ks){
      const int b = ks % 3;
      if (ks + 2 < NKS){ STAGE((ks+2)%3, ks+2); LOADA((ks+2)%3, ks+2); }
      if (ks + 2 < NKS)      asm volatile("s_waitcnt vmcnt(%0)" :: "i"(2*(NW+NA)) : "memory");
      else if (ks + 1 < NKS) asm volatile("s_waitcnt vmcnt(%0)" :: "i"(NW+NA) : "memory");
      else                   asm volatile("s_waitcnt vmcnt(0)" ::: "memory");
      __builtin_amdgcn_sched_barrier(0);
      __builtin_amdgcn_s_barrier();
      __builtin_amdgcn_sched_barrier(0);
      {
        bf8_t a1h = A1H[b], a1l = A1L[b];
        #pragma unroll
        for (int t=0;t<4;t++){
          const int wr = quad*512 + (t*16 + l15)*8;
          bf8_t bh = *(const bf8_t*)&shm.enc[b][0][wr];
          bf8_t bl = *(const bf8_t*)&shm.enc[b][1][wr];
          acc[t] = __builtin_amdgcn_mfma_f32_16x16x32_bf16(a1h, bh, acc[t], 0, 0, 0);
          acc[t] = __builtin_amdgcn_mfma_f32_16x16x32_bf16(a1h, bl, acc[t], 0, 0, 0);
          acc[t] = __builtin_amdgcn_mfma_f32_16x16x32_bf16(a1l, bh, acc[t], 0, 0, 0);
        }
      }
      __builtin_amdgcn_sched_barrier(0);
      asm volatile("s_waitcnt lgkmcnt(0)" ::: "memory");
      __builtin_amdgcn_s_barrier();
      __builtin_amdgcn_sched_barrier(0);
    }

    #pragma unroll
    for (int t=0;t<4;t++){
      int n = n0 + t*16 + l15;
      float bv = bias[n];
      #pragma unroll
      for (int r=0;r<4;r++){
        int row = row0 + wv*16 + quad*4 + r;
        if (row < NND){
          float v = geluf(acc[t][r] + bv);
          unsigned short hb = bf16_rne(v);
          float hf = __uint_as_float(((unsigned)hb) << 16);
          Ch[(size_t)row*DM + n] = hb;
          Cl[(size_t)row*DM + n] = bf16_rne(v - hf);
        }
      }
    }
    return;
  }

  // ================= knn_fixed body (packed float4 + proxy tournament w/ LDS refill) =====
  const int n = blockIdx.x*4 + wv;
  const float xi = cents[2*n];
  const float yi = cents[2*n+1];
  float sx = xi*xi; FPBAR(sx);
  float sy = yi*yi; FPBAR(sy);
  float sqi = sx + sy; FPBAR(sqi);

  const int start = offs[bucketof(xi)];
  const bool isR = lane < 32;
  const int lo = isR ? lane : (lane - 32);

  u64 K0,K1,K2,K3,K4,K5,K6,K7,K8,K9,K10,K11,K12,K13,K14,K15;
  #define KROUND(r, K) { \
    int myp = isR ? (start + (r)*32 + lo) : (start - 1 - (r)*32 - lo); \
    bool act = (myp >= 0) && (myp < NND); \
    float4 cu = make_float4(0.f, 0.f, 0.f, 0.f); \
    int jd = -1; \
    if (act){ cu = sxyid[myp]; jd = __float_as_int(cu.z); } \
    u64 key = make_key(xi, yi, sqi, cu.x, cu.y, jd, n); \
    K = act ? key : ~0ULL; }
  KROUND(0,K0)   KROUND(1,K1)   KROUND(2,K2)   KROUND(3,K3)
  KROUND(4,K4)   KROUND(5,K5)   KROUND(6,K6)   KROUND(7,K7)
  KROUND(8,K8)   KROUND(9,K9)   KROUND(10,K10) KROUND(11,K11)
  KROUND(12,K12) KROUND(13,K13) KROUND(14,K14) KROUND(15,K15)
  #undef KROUND

  // bitonic sort network, 16 keys ascending (80 compare-exchanges, static)
  CE_A(K0,K1)  CE_D(K2,K3)  CE_A(K4,K5)  CE_D(K6,K7)
  CE_A(K8,K9)  CE_D(K10,K11) CE_A(K12,K13) CE_D(K14,K15)
  CE_A(K0,K2)  CE_A(K1,K3)  CE_D(K4,K6)  CE_D(K5,K7)
  CE_A(K8,K10) CE_A(K9,K11) CE_D(K12,K14) CE_D(K13,K15)
  CE_A(K0,K1)  CE_A(K2,K3)  CE_D(K4,K5)  CE_D(K6,K7)
  CE_A(K8,K9)  CE_A(K10,K11) CE_D(K12,K13) CE_D(K14,K15)
  CE_A(K0,K4)  CE_A(K1,K5)  CE_A(K2,K6)  CE_A(K3,K7)
  CE_D(K8,K12) CE_D(K9,K13) CE_D(K10,K14) CE_D(K11,K15)
  CE_A(K0,K2)  CE_A(K1,K3)  CE_A(K4,K6)  CE_A(K5,K7)
  CE_D(K8,K10) CE_D(K9,K11) CE_D(K12,K14) CE_D(K13,K15)
  CE_A(K0,K1)  CE_A(K2,K3)  CE_A(K4,K5)  CE_A(K6,K7)
  CE_D(K8,K9)  CE_D(K10,K11) CE_D(K12,K13) CE_D(K14,K15)
  CE_A(K0,K8)  CE_A(K1,K9)  CE_A(K2,K10) CE_A(K3,K11)
  CE_A(K4,K12) CE_A(K5,K13) CE_A(K6,K14) CE_A(K7,K15)
  CE_A(K0,K4)  CE_A(K1,K5)  CE_A(K2,K6)  CE_A(K3,K7)
  CE_A(K8,K12) CE_A(K9,K13) CE_A(K10,K14) CE_A(K11,K15)
  CE_A(K0,K2)  CE_A(K1,K3)  CE_A(K4,K6)  CE_A(K5,K7)
  CE_A(K8,K10) CE_A(K9,K11) CE_A(K12,K14) CE_A(K13,K15)
  CE_A(K0,K1)  CE_A(K2,K3)  CE_A(K4,K5)  CE_A(K6,K7)
  CE_A(K8,K9)  CE_A(K10,K11) CE_A(K12,K13) CE_A(K14,K15)

  // spill sorted slots 1..11 to the per-wave LDS slice (static ds_writes)
  u64* slice = &shm.knn[wv][0];
  slice[0*64+lane]=K1;  slice[1*64+lane]=K2;  slice[2*64+lane]=K3;
  slice[3*64+lane]=K4;  slice[4*64+lane]=K5;  slice[5*64+lane]=K6;
  slice[6*64+lane]=K7;  slice[7*64+lane]=K8;  slice[8*64+lane]=K9;
  slice[9*64+lane]=K10; slice[10*64+lane]=K11;

  // proxy tournament with LDS refill (slots 1..11) + register fallback (12..15)
  u64 out16 = ~0ULL;
  {
    u64 cur = K0; unsigned curd = (unsigned)(cur >> 32);
    int p = 0;
    for (int r=0;r<KNN;r++){
      u64 k; int who;
      PSELECT(k, who, cur, curd)
      if (lane == r) out16 = k;
      if (lane == who){
        ++p;
        u64 nxt;
        if (p <= 11) nxt = slice[(p-1)*64 + lane];
        else nxt = (p==12)?K12:(p==13)?K13:(p==14)?K14:(p==15)?K15:~0ULL;
        cur = nxt; curd = (unsigned)(nxt >> 32);
      }
    }
  }

  float B = __uint_as_float((unsigned)(__shfl(out16, KNN-1, 64) >> 32));
  const float thr = B*B + 2e-4f;

  const int qr = min(start + RW*32, NND);
  const int ql = max(start - RW*32, 0);
  bool ok;
  {
    bool rok = (qr >= NND);
    if (!rok){
      float xR = sxyid[qr-1].x;
      float dxr = ((float)bucketof(xR)*BW - 8.0f) - xi;
      rok = (dxr > 0.0f) && (dxr*dxr > thr);
    }
    bool lok = (ql <= 0);
    if (!lok){
      float xL = sxyid[ql].x;
      float dxl = xi - ((float)(bucketof(xL)+1)*BW - 8.0f);
      lok = (dxl > 0.0f) && (dxl*dxl > thr);
    }
    ok = rok && lok;
  }
  if (lane == 0 && !ok){
    int s = atomicAdd(ocnt, 1);
    olist[s] = n;
    othr[s] = thr;
  }

  write_outputs(out16, lane, n, idx_out, w_out);
}

// ---------------- bounded rescan for deferred nodes ----------------
// r29-proven ladder + named-scalar tournament (r36 proxy selection).
__global__ __launch_bounds__(256, 4) void knn_ext_r37(
    const float4* __restrict__ sxyid,
    const float* __restrict__ cents, const int* __restrict__ offs,
    const int* __restrict__ olist, const float* __restrict__ othr,
    const int* __restrict__ ocnt,
    int* __restrict__ idx_out, float* __restrict__ w_out)
{
  __shared__ u64 merged[64];         // 4 waves x 16 survivors
  const int lane = threadIdx.x & 63, wv = threadIdx.x >> 6;
  const int cnt = *ocnt;

  for (int slot = blockIdx.x; slot < cnt; slot += gridDim.x){
    const int n = olist[slot];
    const float thr = othr[slot];
    const float rB = __fsqrt_rn(thr) * (1.0f + 2e-6f);
    const float xi = cents[2*n];
    const float yi = cents[2*n+1];
    float sx = xi*xi; FPBAR(sx);
    float sy = yi*yi; FPBAR(sy);
    float sqi = sx + sy; FPBAR(sqi);

    const int bL = bucketof(xi - rB);
    const int bR = bucketof(xi + rB);
    const int posL = offs[bL];
    const int posR = (bR + 1 < NB) ? offs[bR + 1] : NND;

    u64 L[KNN];
    #pragma unroll
    for (int t=0;t<KNN;t++) L[t] = ~0ULL;

    int p = posL + (wv<<6) + lane;
    for (; p + 256 < posR; p += 512){
      float4 c0 = sxyid[p];
      float4 c1 = sxyid[p+256];
      u64 k0 = make_key(xi, yi, sqi, c0.x, c0.y, __float_as_int(c0.z), n);
      u64 k1 = make_key(xi, yi, sqi, c1.x, c1.y, __float_as_int(c1.z), n);
      if (k0 < L[KNN-1]) ladder_insert(L, k0);   // exact: key>=L[15] is a no-op
      if (k1 < L[KNN-1]) ladder_insert(L, k1);
    }
    if (p < posR){
      float4 c0 = sxyid[p];
      u64 k0 = make_key(xi, yi, sqi, c0.x, c0.y, __float_as_int(c0.z), n);
      if (k0 < L[KNN-1]) ladder_insert(L, k0);
    }

    // copy to named scalars (static) -> spill-proof tournament
    u64 K0=L[0], K1=L[1], K2=L[2],  K3=L[3],  K4=L[4],  K5=L[5],  K6=L[6],  K7=L[7],
        K8=L[8], K9=L[9], K10=L[10],K11=L[11],K12=L[12],K13=L[13],K14=L[14],K15=L[15];
    u64 w16 = ~0ULL;
    TOURNEY16(w16, lane)

    if (lane < KNN) merged[(wv<<4) + lane] = w16;
    __syncthreads();
    if (wv == 0){
      u64 out16 = merge64(merged, lane);
      write_outputs(out16, lane, n, idx_out, w_out);
    }
    __syncthreads();   // merged[] reused next slot
  }
}

// ---------------- GEMM: W-in-LDS (depth-2 prefetch) + A-in-registers ----------------
// r30-proven. Used for the two DUAL sage GEMMs.
template<int OUT, bool DUAL, bool BIAS, bool SPLITOUT>
__global__ __launch_bounds__(256, 4) void mm_mfma_r37(
    const unsigned short* __restrict__ A1h, const unsigned short* __restrict__ A1l,
    const unsigned short* __restrict__ A2h, const unsigned short* __restrict__ A2l,
    const unsigned short* __restrict__ W1h, const unsigned short* __restrict__ W1l,
    const unsigned short* __restrict__ W2h, const unsigned short* __restrict__ W2l,
    const float* __restrict__ bias,
    float* __restrict__ Cf, unsigned short* __restrict__ Ch, unsigned short* __restrict__ Cl)
{
  constexpr int NTILW = DUAL ? 4 : 2;      // W tiles per k-step
  constexpr int NW  = DUAL ? 4 : 2;        // W gload_lds per wave per step
  constexpr int NA  = DUAL ? 4 : 2;        // A register loads per lane per step
  constexpr int NCG = OUT / 64;            // 4 or 2
  constexpr int LG  = (NCG == 4) ? 2 : 1;
  constexpr int RTM = (NND + 63) / 64;     // 188
  __shared__ unsigned short sbW[3][NTILW][2048];   // 3 buffers x W tiles x 4KB
  const int lane = threadIdx.x & 63, wv = threadIdx.x >> 6;
  const int bid = blockIdx.x;
  const int xcd = bid & 7;
  const int cg  = (bid >> 3) & (NCG - 1);
  const int rt  = ((bid >> (3 + LG)) << 3) + xcd;
  if (rt >= RTM) return;
  const int row0 = rt*64;
  const int n0 = cg*64;
  const int l15 = lane & 15;
  const int quad = lane >> 4;

  const size_t woff = (size_t)(n0 + lane) * DM;
  const unsigned short* wsrc;
  int wtile, q0;
  if (DUAL){
    wsrc = ((wv==0) ? W1h : (wv==1) ? W1l : (wv==2) ? W2h : W2l) + woff;
    wtile = wv; q0 = 0;
  } else {
    wsrc = ((wv < 2) ? W1h : W1l) + woff;
    wtile = wv >> 1; q0 = (wv & 1) * 2;
  }

  const int am = min(row0 + wv*16 + l15, NND-1);
  const size_t abase = (size_t)am*DM + quad*8;

  f4_t acc[4];
  #pragma unroll
  for (int t=0;t<4;t++) acc[t] = (f4_t){0.f,0.f,0.f,0.f};

  bf8_t A1H[3], A1L[3], A2H[3], A2L[3];

  auto STAGE = [&](int b, int ks){
    if (DUAL){
      #pragma unroll
      for (int j=0;j<4;j++)
        gload16(wsrc + ks*32 + j*8, &sbW[b][wtile][j*512]);
    } else {
      #pragma unroll
      for (int j=0;j<2;j++)
        gload16(wsrc + ks*32 + (q0+j)*8, &sbW[b][wtile][(q0+j)*512]);
    }
  };
  auto LOADA = [&](int s, int ks){
    A1H[s] = *(const bf8_t*)(A1h + abase + ks*32);
    A1L[s] = *(const bf8_t*)(A1l + abase + ks*32);
    if (DUAL){
      A2H[s] = *(const bf8_t*)(A2h + abase + ks*32);
      A2L[s] = *(const bf8_t*)(A2l + abase + ks*32);
    }
  };

  STAGE(0, 0); LOADA(0, 0);
  STAGE(1, 1); LOADA(1, 1);
  constexpr int NKS = DM/32;             // 8
  #pragma unroll
  for (int ks=0; ks<NKS; ++ks){
    const int b = ks % 3;
    if (ks + 2 < NKS){ STAGE((ks+2)%3, ks+2); LOADA((ks+2)%3, ks+2); }
    if (ks + 2 < NKS)      asm volatile("s_waitcnt vmcnt(%0)" :: "i"(2*(NW+NA)) : "memory");
    else if (ks + 1 < NKS) asm volatile("s_waitcnt vmcnt(%0)" :: "i"(NW+NA) : "memory");
    else                   asm volatile("s_waitcnt vmcnt(0)" ::: "memory");
    __builtin_amdgcn_sched_barrier(0);
    __builtin_amdgcn_s_barrier();        // all waves: W tiles for ks complete
    __builtin_amdgcn_sched_barrier(0);
    {
      bf8_t a1h = A1H[b], a1l = A1L[b];
      bf8_t a2h, a2l;
      if (DUAL){ a2h = A2H[b]; a2l = A2L[b]; }
      #pragma unroll
      for (int t=0;t<4;t++){
        const int wr = quad*512 + (t*16 + l15)*8;
        bf8_t bh = *(const bf8_t*)&sbW[b][0][wr];
        bf8_t bl = *(const bf8_t*)&sbW[b][1][wr];
        acc[t] = __builtin_amdgcn_mfma_f32_16x16x32_bf16(a1h, bh, acc[t], 0, 0, 0);
        acc[t] = __builtin_amdgcn_mfma_f32_16x16x32_bf16(a1h, bl, acc[t], 0, 0, 0);
        acc[t] = __builtin_amdgcn_mfma_f32_16x16x32_bf16(a1l, bh, acc[t], 0, 0, 0);
        if (DUAL){
          bf8_t ch = *(const bf8_t*)&sbW[b][2][wr];
          bf8_t cl = *(const bf8_t*)&sbW[b][3][wr];
          acc[t] = __builtin_amdgcn_mfma_f32_16x16x32_bf16(a2h, ch, acc[t], 0, 0, 0);
          acc[t] = __builtin_amdgcn_mfma_f32_16x16x32_bf16(a2h, cl, acc[t], 0, 0, 0);
          acc[t] = __builtin_amdgcn_mfma_f32_16x16x32_bf16(a2l, ch, acc[t], 0, 0, 0);
        }
      }
    }
    __builtin_amdgcn_sched_barrier(0);
    asm volatile("s_waitcnt lgkmcnt(0)" ::: "memory");
    __builtin_amdgcn_s_barrier();        // all waves done reading buffer b
    __builtin_amdgcn_sched_barrier(0);
  }

  #pragma unroll
  for (int t=0;t<4;t++){
    int n = n0 + t*16 + l15;
    float bv = BIAS ? bias[n] : 0.f;
    #pragma unroll
    for (int r=0;r<4;r++){
      int row = row0 + wv*16 + quad*4 + r;
      if (row < NND){
        float v = geluf(acc[t][r] + bv);
        if (SPLITOUT){
          unsigned short hb = bf16_rne(v);
          float hf = __uint_as_float(((unsigned)hb) << 16);
          Ch[(size_t)row*OUT + n] = hb;
          Cl[(size_t)row*OUT + n] = bf16_rne(v - hf);
        } else {
          Cf[(size_t)row*OUT + n] = v;
        }
      }
    }
  }
}

// ---------------- CLASSIFIER: full-row GEMM + fused cls2 dot (r35-proven) ----------------
__global__ __launch_bounds__(256, 4) void cls_fused_r37(
    const unsigned short* __restrict__ A1h, const unsigned short* __restrict__ A1l,
    const unsigned short* __restrict__ W1h, const unsigned short* __restrict__ W1l,
    const float* __restrict__ bias, const float* __restrict__ w2,
    const float* __restrict__ b2,
    void* __restrict__ out, const int* __restrict__ flag)
{
  constexpr int NW = 4, NA = 2;            // vm ops per wave per step
  constexpr int RTM = (NND + 63) / 64;     // 188
  __shared__ unsigned short sbW[3][2][4096];   // 3 buf x {h,l} x 8KB (48KB)
  const int lane = threadIdx.x & 63, wv = threadIdx.x >> 6;
  const int bid = blockIdx.x;
  const int xcd = bid & 7;
  const int rt  = ((bid >> 3) << 3) + xcd;
  if (rt >= RTM) return;
  const int row0 = rt*64;
  const int l15 = lane & 15;
  const int quad = lane >> 4;

  const int am = min(row0 + wv*16 + l15, NND-1);
  const size_t abase = (size_t)am*DM + quad*8;

  f4_t acc[8];
  #pragma unroll
  for (int t=0;t<8;t++) acc[t] = (f4_t){0.f,0.f,0.f,0.f};

  bf8_t A1H[3], A1L[3];

  auto STAGE = [&](int b, int ks){
    #pragma unroll
    for (int j=0;j<4;j++){
      const int g = wv*4 + j;
      const int a = g >> 3, rem = g & 7, q = rem >> 1, half = rem & 1;
      const unsigned short* ws = (a ? W1l : W1h)
          + (size_t)(half*64 + lane)*DM + ks*32 + q*8;
      gload16(ws, &sbW[b][a][q*1024 + half*512]);
    }
  };
  auto LOADA = [&](int s, int ks){
    A1H[s] = *(const bf8_t*)(A1h + abase + ks*32);
    A1L[s] = *(const bf8_t*)(A1l + abase + ks*32);
  };

  STAGE(0, 0); LOADA(0, 0);
  STAGE(1, 1); LOADA(1, 1);
  constexpr int NKS = DM/32;             // 8
  #pragma unroll
  for (int ks=0; ks<NKS; ++ks){
    const int b = ks % 3;
    if (ks + 2 < NKS){ STAGE((ks+2)%3, ks+2); LOADA((ks+2)%3, ks+2); }
    if (ks + 2 < NKS)      asm volatile("s_waitcnt vmcnt(%0)" :: "i"(2*(NW+NA)) : "memory");
    else if (ks + 1 < NKS) asm volatile("s_waitcnt vmcnt(%0)" :: "i"(NW+NA) : "memory");
    else                   asm volatile("s_waitcnt vmcnt(0)" ::: "memory");
    __builtin_amdgcn_sched_barrier(0);
    __builtin_amdgcn_s_barrier();
    __builtin_amdgcn_sched_barrier(0);
    {
      bf8_t a1h = A1H[b], a1l = A1L[b];
      #pragma unroll
      for (int t=0;t<8;t++){
        const int wr = quad*1024 + (t*16 + l15)*8;
        bf8_t bh = *(const bf8_t*)&sbW[b][0][wr];
        bf8_t bl = *(const bf8_t*)&sbW[b][1][wr];
        acc[t] = __builtin_amdgcn_mfma_f32_16x16x32_bf16(a1h, bh, acc[t], 0, 0, 0);
        acc[t] = __builtin_amdgcn_mfma_f32_16x16x32_bf16(a1h, bl, acc[t], 0, 0, 0);
        acc[t] = __builtin_amdgcn_mfma_f32_16x16x32_bf16(a1l, bh, acc[t], 0, 0, 0);
      }
    }
    __builtin_amdgcn_sched_barrier(0);
    asm volatile("s_waitcnt lgkmcnt(0)" ::: "memory");
    __builtin_amdgcn_s_barrier();
    __builtin_amdgcn_sched_barrier(0);
  }

  // epilogue: gelu + dot(w2) + 16-lane reduce + sigmoid -> out
  const int is_bf16 = *flag;
  float partial0=0.f, partial1=0.f, partial2=0.f, partial3=0.f;
  #pragma unroll
  for (int t=0;t<8;t++){
    const int c = t*16 + l15;
    const float bv = bias[c];
    const float wc = w2[c];
    partial0 = fmaf(geluf(acc[t][0] + bv), wc, partial0);
    partial1 = fmaf(geluf(acc[t][1] + bv), wc, partial1);
    partial2 = fmaf(geluf(acc[t][2] + bv), wc, partial2);
    partial3 = fmaf(geluf(acc[t][3] + bv), wc, partial3);
  }
  #pragma unroll
  for (int o=1; o<16; o<<=1){
    partial0 += __shfl_xor(partial0, o, 64);
    partial1 += __shfl_xor(partial1, o, 64);
    partial2 += __shfl_xor(partial2, o, 64);
    partial3 += __shfl_xor(partial3, o, 64);
  }
  if (l15 == 0){
    const float bb = b2[0];
    #pragma unroll
    for (int r=0;r<4;r++){
      float s = (r==0)?partial0:(r==1)?partial1:(r==2)?partial2:partial3;
      int row = row0 + wv*16 + quad*4 + r;
      if (row < NND){
        float v = 1.0f / (1.0f + expf(-(s + bb)));
        if (is_bf16) ((__hip_bfloat16*)out)[row] = __float2bfloat16(v);
        else         ((float*)out)[row] = v;
      }
    }
  }
}

// ---------------- weighted neighbor aggregation ----------------
__global__ __launch_bounds__(256) void agg_kernel_r37(
    const unsigned short* __restrict__ hh, const unsigned short* __restrict__ hl,
    const int* __restrict__ idx, const float* __restrict__ w,
    unsigned short* __restrict__ oh, unsigned short* __restrict__ ol)
{
  const int lane = threadIdx.x & 63, wid = threadIdx.x >> 6;
  const int n = blockIdx.x*4 + wid;
  const int base = n*KNN;
  const int c = lane*4;
  float4 acc = make_float4(0.f,0.f,0.f,0.f);
  for (int k=0;k<KNN;k++){
    int j = idx[base+k];
    float wk = w[base+k];
    ushort4 vh = *(const ushort4*)(hh + (size_t)j*DM + c);
    ushort4 vl = *(const ushort4*)(hl + (size_t)j*DM + c);
    acc.x = fmaf(wk, bfpair(vh.x, vl.x), acc.x);
    acc.y = fmaf(wk, bfpair(vh.y, vl.y), acc.y);
    acc.z = fmaf(wk, bfpair(vh.z, vl.z), acc.z);
    acc.w = fmaf(wk, bfpair(vh.w, vl.w), acc.w);
  }
  unsigned short h0 = bf16_rne(acc.x); float f0 = __uint_as_float(((unsigned)h0) << 16);
  unsigned short h1 = bf16_rne(acc.y); float f1 = __uint_as_float(((unsigned)h1) << 16);
  unsigned short h2 = bf16_rne(acc.z); float f2 = __uint_as_float(((unsigned)h2) << 16);
  unsigned short h3 = bf16_rne(acc.w); float f3 = __uint_as_float(((unsigned)h3) << 16);
  ushort4 sh = make_ushort4(h0, h1, h2, h3);
  ushort4 sl = make_ushort4(bf16_rne(acc.x - f0), bf16_rne(acc.y - f1),
                            bf16_rne(acc.z - f2), bf16_rne(acc.w - f3));
  *(ushort4*)(oh + (size_t)n*DM + c) = sh;
  *(ushort4*)(ol + (size_t)n*DM + c) = sl;
}

// ---------------- h = h + layernorm(tmp)*g + b  (h stored as bf16 hi/lo) ----------------
__global__ __launch_bounds__(256) void ln_res_kernel_r37(
    unsigned short* __restrict__ hh, unsigned short* __restrict__ hl,
    const float* __restrict__ tmp, const float* __restrict__ g, const float* __restrict__ b)
{
  const int lane = threadIdx.x & 63, wid = threadIdx.x >> 6;
  const int n = blockIdx.x*4 + wid;
  float4 x = *(const float4*)(tmp + (size_t)n*DM + lane*4);
  float s = (x.x + x.y) + (x.z + x.w);
  #pragma unroll
  for (int off=32; off>0; off>>=1) s += __shfl_xor(s, off, 64);
  float mu = s * (1.0f/DM);
  float dx0 = x.x-mu, dx1 = x.y-mu, dx2 = x.z-mu, dx3 = x.w-mu;
  float v = (dx0*dx0 + dx1*dx1) + (dx2*dx2 + dx3*dx3);
  #pragma unroll
  for (int off=32; off>0; off>>=1) v += __shfl_xor(v, off, 64);
  float rs = 1.0f / sqrtf(v * (1.0f/DM) + 1e-5f);
  int c = lane*4;
  float4 gv = *(const float4*)(g + c);
  float4 bv = *(const float4*)(b + c);
  ushort4 vh = *(const ushort4*)(hh + (size_t)n*DM + c);
  ushort4 vl = *(const ushort4*)(hl + (size_t)n*DM + c);
  float o0 = bfpair(vh.x, vl.x) + dx0*rs*gv.x + bv.x;
  float o1 = bfpair(vh.y, vl.y) + dx1*rs*gv.y + bv.y;
  float o2 = bfpair(vh.z, vl.z) + dx2*rs*gv.z + bv.z;
  float o3 = bfpair(vh.w, vl.w) + dx3*rs*gv.w + bv.w;
  unsigned short h0 = bf16_rne(o0); float f0 = __uint_as_float(((unsigned)h0) << 16);
  unsigned short h1 = bf16_rne(o1); float f1 = __uint_as_float(((unsigned)h1) << 16);
  unsigned short h2 = bf16_rne(o2); float f2 = __uint_as_float(((unsigned)h2) << 16);
  unsigned short h3 = bf16_rne(o3); float f3 = __uint_as_float(((unsigned)h3) << 16);
  *(ushort4*)(hh + (size_t)n*DM + c) = make_ushort4(h0, h1, h2, h3);
  *(ushort4*)(hl + (size_t)n*DM + c) = make_ushort4(bf16_rne(o0 - f0), bf16_rne(o1 - f1),
                                                    bf16_rne(o2 - f2), bf16_rne(o3 - f3));
}

extern "C" void kernel_launch(void* const* d_in, const int* in_sizes, int n_in,
                              void* d_out, int out_size, void* d_ws, size_t ws_size,
                              hipStream_t stream)
{
  // ---- workspace layout (~46.6 MB), fully rewritten every call ----
  char* base = (char*)d_ws;
  int*   flag = (int*)base;                                   // 16 B slot
  float* wreg = (float*)(base + 16);
  static const int sizes[16] = {
    NND*256, NND*2, 256*256, 256, 256*256, 256*256, 256, 256,
    256*256, 256*256, 256, 256, 128*256, 128, 128, 1
  };
  float* ptrs[16];
  {
    float* p = wreg;
    for (int i = 2; i < 16; i++){ ptrs[i] = p; p += (sizes[i] + 3) & ~3; }
    ptrs[1] = p;                          // cents  [24,000]
    p += NND*2;
    ptrs[0] = p;                          // feats region  [3,072,000 floats]
  }
  float* F    = ptrs[0];                  // f32 tmp view of feats region
  unsigned short* fh = (unsigned short*)ptrs[0];          // feats hi
  unsigned short* fl = fh + (size_t)NND*DM;               // feats lo
  float* C    = ptrs[1];
  float* hbase = F + (size_t)NND*DM;
  unsigned short* h_hi = (unsigned short*)hbase;
  unsigned short* h_lo = h_hi + (size_t)NND*DM;
  float* abase = hbase + (size_t)NND*DM;
  unsigned short* a_hi = (unsigned short*)abase;
  unsigned short* a_lo = a_hi + (size_t)NND*DM;
  float* hid  = abase + (size_t)NND*DM;   // (region retained; cls2 fused away)
  int*  gidx  = (int*)(hid + (size_t)NND*128);
  float* gw   = (float*)(gidx + (size_t)NND*KNN);
  // knn pre-pass scratch (packed float4 candidates)
  float4* sxyid = (float4*)(gw + (size_t)NND*KNN);
  int*    hist  = (int*)(sxyid + NND);
  int*    cursor= hist + NB;
  int*    offs  = cursor + NB;
  int*    ocnt  = offs + NB;
  int*    olist = ocnt + 4;               // 16B pad keeps wh 16B-aligned
  float*  othr  = (float*)(olist + NND);  // thr per deferred node
  // bf16 hi/lo weights (enc_w | g1_ws | g1_wn | g2_ws | g2_wn | cls_w1), 16B-aligned
  unsigned short* wh = (unsigned short*)(((uintptr_t)(othr + NND) + 15) & ~(uintptr_t)15);
  unsigned short* wl = wh + NWELEM;

  // ---- dtype detect + decode (weights split to hi/lo IN decode; r34-proven) ----
  detect_kernel_r37<<<1, 256, 0, stream>>>((const unsigned*)d_in[1], 4096,
                                           (const unsigned*)d_in[0], 16384, flag);
  SegTable t;
  int total = 0;
  for (int i = 0; i < 16; i++){
    t.src[i] = d_in[i];
    t.dst[i] = ptrs[i];
    t.cnt[i] = sizes[i];
    t.wofs[i] = -1;
    total += sizes[i];
  }
  t.dst[0] = nullptr;       // feats handled via fh/fl
  t.wofs[2]  = 0;           // enc_w
  t.wofs[4]  = 65536;       // g1_ws
  t.wofs[5]  = 131072;      // g1_wn
  t.wofs[8]  = 196608;      // g2_ws
  t.wofs[9]  = 262144;      // g2_wn
  t.wofs[12] = 327680;      // cls_w1
  t.total = total;
  decode_kernel_r37<<<(total + 255)/256, 256, 0, stream>>>(t, fh, fl, wh, wl, flag);

  const float* enc_b  = ptrs[3];
  const float* g1_g   = ptrs[6];  const float* g1_b   = ptrs[7];
  const float* g2_g   = ptrs[10]; const float* g2_b   = ptrs[11];
  const float* cls_b1 = ptrs[13];
  const float* cls_w2 = ptrs[14]; const float* cls_b2 = ptrs[15];

  dim3 b256(256);
  // knn pre-pass: bucket counting sort by x (+ zero outlier counter)
  zero_kernel_r37<<<(NB + 255)/256, b256, 0, stream>>>(hist, cursor, ocnt);
  count_kernel_r37<<<(NND + 255)/256, b256, 0, stream>>>(C, hist);
  scan_kernel_r37<<<1, 1024, 0, stream>>>(hist, offs);
  scatter_kernel_r37<<<(NND + 255)/256, b256, 0, stream>>>(C, offs, cursor, sxyid);
  // swizzled grids: 24 rt-groups of 8 XCD-slots x NCG col-groups
  const int G4 = 24 * 8 * 4;   // 768  (OUT=256)
  // FUSED: knn_fixed (blocks 0..2999) || encoder GEMM (blocks 3000..3767)
  fused_enc_knn_r37<<<KBLK + G4, b256, 0, stream>>>(
      fh, fl, wh + 0, wl + 0, enc_b, h_hi, h_lo,
      sxyid, C, offs, gidx, gw, ocnt, olist, othr);
  knn_ext_r37<<<2048, b256, 0, stream>>>(sxyid, C, offs, olist, othr, ocnt, gidx, gw);
  // sage layer 1 (tmp := F region, feats dead after encoder)
  agg_kernel_r37<<<NND/4, b256, 0, stream>>>(h_hi, h_lo, gidx, gw, a_hi, a_lo);
  mm_mfma_r37<256,true,false,false><<<G4, b256, 0, stream>>>(h_hi, h_lo, a_hi, a_lo,
      wh + 65536, wl + 65536, wh + 131072, wl + 131072, nullptr, F, nullptr, nullptr);
  ln_res_kernel_r37<<<NND/4, b256, 0, stream>>>(h_hi, h_lo, F, g1_g, g1_b);
  // sage layer 2
  agg_kernel_r37<<<NND/4, b256, 0, stream>>>(h_hi, h_lo, gidx, gw, a_hi, a_lo);
  mm_mfma_r37<256,true,false,false><<<G4, b256, 0, stream>>>(h_hi, h_lo, a_hi, a_lo,
      wh + 196608, wl + 196608, wh + 262144, wl + 262144, nullptr, F, nullptr, nullptr);
  ln_res_kernel_r37<<<NND/4, b256, 0, stream>>>(h_hi, h_lo, F, g2_g, g2_b);
  // classifier: full-row GEMM + fused cls2 dot -> d_out (192 blocks)
  cls_fused_r37<<<24*8, b256, 0, stream>>>(h_hi, h_lo,
      wh + 327680, wl + 327680, cls_b1, cls_w2, cls_b2, d_out, flag);
}

// Round 20
// 363.574 us; speedup vs baseline: 1.0349x; 1.0302x over previous
//
#include <hip/hip_runtime.h>
#include <hip/hip_bf16.h>
#include <stdint.h>

#define NND 12000
#define DM  256
#define KNN 16
#define NB  4096          // x-buckets
#define BW  0.00390625f   // bucket width = 1/256 over [-8, 8)
#define RW  16            // fixed-window rounds (16*64 = 1024 candidates)
#define NWELEM 360448     // total weight elements converted to bf16 hi/lo
#define KBLK (NND/4)      // 3000 knn blocks first (r32 ordering, measured best)

// Opaque register barrier: prevents FMA contraction (r9: made knn bit-match numpy
// -> absmax 0.0. DO NOT REMOVE from knn path).
#define FPBAR(x) asm volatile("" : "+v"(x))

typedef unsigned long long u64;
typedef __attribute__((ext_vector_type(8))) short bf8_t;   // 8 bf16 (4 VGPRs)
typedef __attribute__((ext_vector_type(4))) float f4_t;

__device__ __forceinline__ float geluf(float x){ return 0.5f*x*(1.0f + erff(x*0.70710678118654752f)); }
__device__ __forceinline__ int bucketof(float x){
  int b = (int)floorf((x + 8.0f) * 256.0f);
  return min(max(b, 0), NB-1);
}

__device__ __forceinline__ unsigned short bf16_rne(float x){
  unsigned u = __float_as_uint(x);
  unsigned r = u + 0x7FFF + ((u >> 16) & 1);
  return (unsigned short)(r >> 16);
}

__device__ __forceinline__ float bfpair(unsigned short h, unsigned short l){
  return __uint_as_float(((unsigned)h) << 16) + __uint_as_float(((unsigned)l) << 16);
}

// async global->LDS, 16B per lane. LDS dest is WAVE-UNIFORM base + lane*16;
// global src is per-lane. Completion tracked by vmcnt.
__device__ __forceinline__ void gload16(const unsigned short* g, unsigned short* l){
  __builtin_amdgcn_global_load_lds(
      (__attribute__((address_space(1))) void*)g,
      (__attribute__((address_space(3))) void*)l, 16, 0, 0);
}

// bit-exact numpy distance key (r9-verified). Low 32 bits = original node idx.
__device__ __forceinline__ u64 make_key(float xi, float yi, float sqi,
                                        float cx, float cy, int jd, int self){
  float ax = cx*cx;  FPBAR(ax);
  float ay = cy*cy;  FPBAR(ay);
  float sqj = ax + ay;   FPBAR(sqj);
  float px = xi*cx;    FPBAR(px);
  float py = yi*cy;    FPBAR(py);
  float dt = px + py;    FPBAR(dt);            // NO-FMA dot
  float two_dt = 2.0f*dt;  FPBAR(two_dt);
  float ss = sqi + sqj;    FPBAR(ss);
  float d2 = ss - two_dt;  FPBAR(d2);
  float dist = __fsqrt_rn(fmaxf(d2, 0.0f));
  u64 key = ((u64)__float_as_uint(dist) << 32) | (unsigned)jd;
  return (jd == self) ? ~0ULL : key;
}

__device__ __forceinline__ void ladder_insert(u64* L, u64 key){
  bool c[KNN];
  #pragma unroll
  for (int t=0;t<KNN;t++) c[t] = key < L[t];
  #pragma unroll
  for (int t=KNN-1;t>=1;t--) L[t] = c[t-1] ? L[t-1] : (c[t] ? key : L[t]);
  L[0] = c[0] ? key : L[0];
}

// merge 64 candidate keys (one per lane) -> lane r holds r-th smallest (r<16).
__device__ __forceinline__ u64 merge64(const u64* m, int lane)
{
  u64 cur = m[lane];
  u64 out16 = ~0ULL;
  for (int r=0;r<KNN;r++){
    u64 k = cur; int who = lane;
    #pragma unroll
    for (int o=32;o>0;o>>=1){
      u64 ok = __shfl_xor(k, o, 64);
      int ow = __shfl_xor(who, o, 64);
      if (ok < k){ k = ok; who = ow; }
    }
    if (lane == r) out16 = k;
    if (lane == who) cur = ~0ULL;
  }
  return out16;
}

__device__ __forceinline__ void write_outputs(u64 out16, int lane, int n,
    int* __restrict__ idx_out, float* __restrict__ w_out)
{
  if (lane < KNN) idx_out[(size_t)n*KNN + lane] = (int)(unsigned)(out16 & 0xFFFFFFFFull);
  u64 kt[KNN];
  #pragma unroll
  for (int t=0;t<KNN;t++) kt[t] = __shfl(out16, t, 64);
  float inv[KNN];
  #pragma unroll
  for (int t=0;t<KNN;t++){
    float d = __uint_as_float((unsigned)(kt[t] >> 32));
    inv[t] = __fdiv_rn(1.0f, fmaxf(d, 1e-4f));
  }
  float r8v[8];
  #pragma unroll
  for (int t=0;t<8;t++){ r8v[t] = inv[t] + inv[t+8]; FPBAR(r8v[t]); }
  float s01 = r8v[0]+r8v[1]; FPBAR(s01);
  float s23 = r8v[2]+r8v[3]; FPBAR(s23);
  float s45 = r8v[4]+r8v[5]; FPBAR(s45);
  float s67 = r8v[6]+r8v[7]; FPBAR(s67);
  float sA = s01+s23; FPBAR(sA);
  float sB = s45+s67; FPBAR(sB);
  float s = sA + sB;
  s = fmaxf(s, 1e-8f);
  if (lane < KNN){
    float d = __uint_as_float((unsigned)(out16 >> 32));
    float invL = __fdiv_rn(1.0f, fmaxf(d, 1e-4f));
    w_out[(size_t)n*KNN + lane] = __fdiv_rn(invL, s);
  }
}

// compare-exchange macros for the bitonic network (named scalars only —
// r20/r28 lesson: u64 ARRAYS mutated through pointers/under exec-mask get
// lowered to scratch (VGPR 28/32 signatures). Named scalars stay in regs.
#define CE_A(x,y) { u64 mn_=(x)<(y)?(x):(y); u64 mx_=(x)<(y)?(y):(x); (x)=mn_; (y)=mx_; }
#define CE_D(x,y) { u64 mn_=(x)<(y)?(x):(y); u64 mx_=(x)<(y)?(y):(x); (x)=mx_; (y)=mn_; }

// r36-proven: EXACT wave-min of 64 head keys via 32-bit DISTANCE-PROXY
// butterfly. Key = (dist_bits<<32)|idx with positive-float dist -> min dist
// via u32 v_min butterfly (half the u64 cost). Single-match fast path is the
// exact u64 min; ties (wave-uniform rare branch) fall back to full u64
// butterfly. Bit-exact incl. all-sentinel rounds (tie path, who=ffs=0).
#define PSELECT(k, who, cur, curd) {                                \
    unsigned d_ = curd;                                             \
    _Pragma("unroll")                                               \
    for (int o_=32;o_>0;o_>>=1){                                    \
      unsigned od_ = __shfl_xor(d_, o_, 64);                        \
      d_ = min(d_, od_);                                            \
    }                                                               \
    u64 ball_ = __ballot(curd == d_);                               \
    if (ball_ & (ball_ - 1)){                                       \
      u64 c2_ = (curd == d_) ? cur : ~0ULL;                         \
      _Pragma("unroll")                                             \
      for (int o_=32;o_>0;o_>>=1){                                  \
        u64 oc_ = __shfl_xor(c2_, o_, 64);                          \
        if (oc_ < c2_) c2_ = oc_;                                   \
      }                                                             \
      k = c2_;                                                      \
      who = __ffsll(__ballot(cur == k)) - 1;                        \
    } else {                                                        \
      who = __ffsll(ball_) - 1;                                     \
      k = __shfl(cur, who, 64);                                     \
    }                                                               \
  }

// proxy tournament over NAMED scalars K0..K15 with REGISTER-SHIFT refill
// (r35 structure + r36 proxy; r37's LDS refill caused 1.5M bank conflicts
// and a 5us regression -> reverted).
#define TOURNEY16(out16, lane) {                                   \
    u64 cur = K0; unsigned curd = (unsigned)(cur >> 32);           \
    for (int r_=0;r_<KNN;r_++){                                    \
      u64 k_; int who_;                                            \
      PSELECT(k_, who_, cur, curd)                                 \
      if ((lane) == r_) out16 = k_;                                \
      if ((lane) == who_){                                         \
        K0=K1; K1=K2; K2=K3; K3=K4; K4=K5; K5=K6; K6=K7; K7=K8;    \
        K8=K9; K9=K10; K10=K11; K11=K12; K12=K13; K13=K14;         \
        K14=K15; K15=~0ULL;                                        \
        cur = K0; curd = (unsigned)(cur >> 32);                    \
      }                                                            \
    }                                                              \
  }

// ---------------- dtype detection (proven: picks f32 here) ----------------
__global__ __launch_bounds__(256) void detect_kernel_r38(
    const unsigned* __restrict__ a, int na,
    const unsigned* __restrict__ b, int nb, int* __restrict__ flag)
{
  __shared__ int cnt;
  if (threadIdx.x == 0) cnt = 0;
  __syncthreads();
  int c = 0;
  for (int i = threadIdx.x; i < na; i += 256){
    int ex = (a[i] >> 7) & 0xFF;
    c += (ex >= 113 && ex <= 131) ? 1 : 0;
  }
  for (int i = threadIdx.x; i < nb; i += 256){
    int ex = (b[i] >> 7) & 0xFF;
    c += (ex >= 113 && ex <= 131) ? 1 : 0;
  }
  atomicAdd(&cnt, c);
  __syncthreads();
  if (threadIdx.x == 0) *flag = (cnt > (na + nb) / 2) ? 1 : 0;
}

// ---------------- decode all inputs (fused weight hi/lo split; r34-proven) ----------------
struct SegTable {
  const void* src[16];
  float*      dst[16];
  int         cnt[16];
  int         wofs[16];   // >=0: offset into wh/wl for weight segs, else -1
  int         total;
};

__global__ __launch_bounds__(256) void decode_kernel_r38(SegTable t,
    unsigned short* __restrict__ fh, unsigned short* __restrict__ fl,
    unsigned short* __restrict__ dh, unsigned short* __restrict__ dl,
    const int* __restrict__ flag)
{
  const int is_bf16 = *flag;
  for (int e = blockIdx.x*256 + threadIdx.x; e < t.total; e += gridDim.x*256){
    int rem = e, s = 0;
    while (rem >= t.cnt[s]){ rem -= t.cnt[s]; ++s; }
    float v;
    if (is_bf16) v = __uint_as_float(((unsigned)((const unsigned short*)t.src[s])[rem]) << 16);
    else         v = ((const float*)t.src[s])[rem];
    if (s == 0){
      unsigned short hb = bf16_rne(v);
      float hf = __uint_as_float(((unsigned)hb) << 16);
      fh[rem] = hb;
      fl[rem] = bf16_rne(v - hf);
    } else {
      int wo = t.wofs[s];
      if (wo >= 0){
        unsigned short hb = bf16_rne(v);
        float hf = __uint_as_float(((unsigned)hb) << 16);
        dh[wo + rem] = hb;
        dl[wo + rem] = bf16_rne(v - hf);
      } else {
        t.dst[s][rem] = v;
      }
    }
  }
}

// ---------------- bucket pre-pass ----------------
__global__ __launch_bounds__(256) void zero_kernel_r38(int* __restrict__ hist, int* __restrict__ cursor,
                                                       int* __restrict__ ocnt)
{
  int t = blockIdx.x*256 + threadIdx.x;
  if (t < NB){ hist[t] = 0; cursor[t] = 0; }
  if (blockIdx.x == 0 && threadIdx.x == 0) *ocnt = 0;
}

__global__ __launch_bounds__(256) void count_kernel_r38(const float* __restrict__ cents,
                                                        int* __restrict__ hist)
{
  int i = blockIdx.x*256 + threadIdx.x;
  if (i < NND) atomicAdd(&hist[bucketof(cents[2*i])], 1);
}

__global__ __launch_bounds__(1024) void scan_kernel_r38(const int* __restrict__ hist,
                                                        int* __restrict__ offs)
{
  __shared__ int s[1024];
  int t = threadIdx.x;
  int h0 = hist[t*4], h1 = hist[t*4+1], h2 = hist[t*4+2], h3 = hist[t*4+3];
  int tot = h0+h1+h2+h3;
  s[t] = tot;
  __syncthreads();
  for (int d=1; d<1024; d<<=1){
    int v = (t >= d) ? s[t-d] : 0;
    __syncthreads();
    s[t] += v;
    __syncthreads();
  }
  int excl = s[t] - tot;
  offs[t*4]   = excl;
  offs[t*4+1] = excl + h0;
  offs[t*4+2] = excl + h0 + h1;
  offs[t*4+3] = excl + h0 + h1 + h2;
}

// scatter packs (x, y, bitcast(id)) into ONE float4 (r35-proven).
__global__ __launch_bounds__(256) void scatter_kernel_r38(const float* __restrict__ cents,
    const int* __restrict__ offs, int* __restrict__ cursor,
    float4* __restrict__ sxyid)
{
  int i = blockIdx.x*256 + threadIdx.x;
  if (i < NND){
    float x = cents[2*i], y = cents[2*i+1];
    int b = bucketof(x);
    int pos = offs[b] + atomicAdd(&cursor[b], 1);
    sxyid[pos] = make_float4(x, y, __int_as_float(i), 0.f);
  }
}

// ---------------- FUSED: encoder GEMM (blocks >= KBLK) || knn_fixed (blocks < KBLK) ----------------
// r32-proven structure; r38: knn tournament = PSELECT proxy + register-shift
// refill (NO LDS touch on the knn path -> bank conflicts back to 0).
__global__ __launch_bounds__(256, 4) void fused_enc_knn_r38(
    // encoder args
    const unsigned short* __restrict__ A1h, const unsigned short* __restrict__ A1l,
    const unsigned short* __restrict__ W1h, const unsigned short* __restrict__ W1l,
    const float* __restrict__ bias,
    unsigned short* __restrict__ Ch, unsigned short* __restrict__ Cl,
    // knn args
    const float4* __restrict__ sxyid,
    const float* __restrict__ cents, const int* __restrict__ offs,
    int* __restrict__ idx_out, float* __restrict__ w_out,
    int* __restrict__ ocnt, int* __restrict__ olist, float* __restrict__ othr)
{
  __shared__ unsigned short sbW[3][2][2048];   // 24KB, encoder path only
  const int lane = threadIdx.x & 63, wv = threadIdx.x >> 6;

  if (blockIdx.x >= KBLK){
    // ================= encoder body (mm_mfma_r30 <256,false,true,true>) ===========
    constexpr int NW = 2, NA = 2;
    constexpr int NCG = 4, LG = 2;
    constexpr int RTM = (NND + 63) / 64;   // 188
    const int ebid = blockIdx.x - KBLK;
    const int xcd = ebid & 7;
    const int cg  = (ebid >> 3) & (NCG - 1);
    const int rt  = ((ebid >> (3 + LG)) << 3) + xcd;
    if (rt >= RTM) return;
    const int row0 = rt*64;
    const int n0 = cg*64;
    const int l15 = lane & 15;
    const int quad = lane >> 4;

    const size_t woff = (size_t)(n0 + lane) * DM;
    const unsigned short* wsrc = ((wv < 2) ? W1h : W1l) + woff;
    const int wtile = wv >> 1, q0 = (wv & 1) * 2;

    const int am = min(row0 + wv*16 + l15, NND-1);
    const size_t abase = (size_t)am*DM + quad*8;

    f4_t acc[4];
    #pragma unroll
    for (int t=0;t<4;t++) acc[t] = (f4_t){0.f,0.f,0.f,0.f};

    bf8_t A1H[3], A1L[3];

    auto STAGE = [&](int b, int ks){
      #pragma unroll
      for (int j=0;j<2;j++)
        gload16(wsrc + ks*32 + (q0+j)*8, &sbW[b][wtile][(q0+j)*512]);
    };
    auto LOADA = [&](int s, int ks){
      A1H[s] = *(const bf8_t*)(A1h + abase + ks*32);
      A1L[s] = *(const bf8_t*)(A1l + abase + ks*32);
    };

    STAGE(0, 0); LOADA(0, 0);
    STAGE(1, 1); LOADA(1, 1);
    constexpr int NKS = DM/32;             // 8
    #pragma unroll
    for (int ks=0; ks<NKS; ++ks){
      const int b = ks % 3;
      if (ks + 2 < NKS){ STAGE((ks+2)%3, ks+2); LOADA((ks+2)%3, ks+2); }
      if (ks + 2 < NKS)      asm volatile("s_waitcnt vmcnt(%0)" :: "i"(2*(NW+NA)) : "memory");
      else if (ks + 1 < NKS) asm volatile("s_waitcnt vmcnt(%0)" :: "i"(NW+NA) : "memory");
      else                   asm volatile("s_waitcnt vmcnt(0)" ::: "memory");
      __builtin_amdgcn_sched_barrier(0);
      __builtin_amdgcn_s_barrier();
      __builtin_amdgcn_sched_barrier(0);
      {
        bf8_t a1h = A1H[b], a1l = A1L[b];
        #pragma unroll
        for (int t=0;t<4;t++){
          const int wr = quad*512 + (t*16 + l15)*8;
          bf8_t bh = *(const bf8_t*)&sbW[b][0][wr];
          bf8_t bl = *(const bf8_t*)&sbW[b][1][wr];
          acc[t] = __builtin_amdgcn_mfma_f32_16x16x32_bf16(a1h, bh, acc[t], 0, 0, 0);
          acc[t] = __builtin_amdgcn_mfma_f32_16x16x32_bf16(a1h, bl, acc[t], 0, 0, 0);
          acc[t] = __builtin_amdgcn_mfma_f32_16x16x32_bf16(a1l, bh, acc[t], 0, 0, 0);
        }
      }
      __builtin_amdgcn_sched_barrier(0);
      asm volatile("s_waitcnt lgkmcnt(0)" ::: "memory");
      __builtin_amdgcn_s_barrier();
      __builtin_amdgcn_sched_barrier(0);
    }

    #pragma unroll
    for (int t=0;t<4;t++){
      int n = n0 + t*16 + l15;
      float bv = bias[n];
      #pragma unroll
      for (int r=0;r<4;r++){
        int row = row0 + wv*16 + quad*4 + r;
        if (row < NND){
          float v = geluf(acc[t][r] + bv);
          unsigned short hb = bf16_rne(v);
          float hf = __uint_as_float(((unsigned)hb) << 16);
          Ch[(size_t)row*DM + n] = hb;
          Cl[(size_t)row*DM + n] = bf16_rne(v - hf);
        }
      }
    }
    return;
  }

  // ================= knn_fixed body (packed float4 + proxy register tournament) =====
  const int n = blockIdx.x*4 + wv;
  const float xi = cents[2*n];
  const float yi = cents[2*n+1];
  float sx = xi*xi; FPBAR(sx);
  float sy = yi*yi; FPBAR(sy);
  float sqi = sx + sy; FPBAR(sqi);

  const int start = offs[bucketof(xi)];
  const bool isR = lane < 32;
  const int lo = isR ? lane : (lane - 32);

  u64 K0,K1,K2,K3,K4,K5,K6,K7,K8,K9,K10,K11,K12,K13,K14,K15;
  #define KROUND(r, K) { \
    int myp = isR ? (start + (r)*32 + lo) : (start - 1 - (r)*32 - lo); \
    bool act = (myp >= 0) && (myp < NND); \
    float4 cu = make_float4(0.f, 0.f, 0.f, 0.f); \
    int jd = -1; \
    if (act){ cu = sxyid[myp]; jd = __float_as_int(cu.z); } \
    u64 key = make_key(xi, yi, sqi, cu.x, cu.y, jd, n); \
    K = act ? key : ~0ULL; }
  KROUND(0,K0)   KROUND(1,K1)   KROUND(2,K2)   KROUND(3,K3)
  KROUND(4,K4)   KROUND(5,K5)   KROUND(6,K6)   KROUND(7,K7)
  KROUND(8,K8)   KROUND(9,K9)   KROUND(10,K10) KROUND(11,K11)
  KROUND(12,K12) KROUND(13,K13) KROUND(14,K14) KROUND(15,K15)
  #undef KROUND

  // bitonic sort network, 16 keys ascending (80 compare-exchanges, static)
  CE_A(K0,K1)  CE_D(K2,K3)  CE_A(K4,K5)  CE_D(K6,K7)
  CE_A(K8,K9)  CE_D(K10,K11) CE_A(K12,K13) CE_D(K14,K15)
  CE_A(K0,K2)  CE_A(K1,K3)  CE_D(K4,K6)  CE_D(K5,K7)
  CE_A(K8,K10) CE_A(K9,K11) CE_D(K12,K14) CE_D(K13,K15)
  CE_A(K0,K1)  CE_A(K2,K3)  CE_D(K4,K5)  CE_D(K6,K7)
  CE_A(K8,K9)  CE_A(K10,K11) CE_D(K12,K13) CE_D(K14,K15)
  CE_A(K0,K4)  CE_A(K1,K5)  CE_A(K2,K6)  CE_A(K3,K7)
  CE_D(K8,K12) CE_D(K9,K13) CE_D(K10,K14) CE_D(K11,K15)
  CE_A(K0,K2)  CE_A(K1,K3)  CE_A(K4,K6)  CE_A(K5,K7)
  CE_D(K8,K10) CE_D(K9,K11) CE_D(K12,K14) CE_D(K13,K15)
  CE_A(K0,K1)  CE_A(K2,K3)  CE_A(K4,K5)  CE_A(K6,K7)
  CE_D(K8,K9)  CE_D(K10,K11) CE_D(K12,K13) CE_D(K14,K15)
  CE_A(K0,K8)  CE_A(K1,K9)  CE_A(K2,K10) CE_A(K3,K11)
  CE_A(K4,K12) CE_A(K5,K13) CE_A(K6,K14) CE_A(K7,K15)
  CE_A(K0,K4)  CE_A(K1,K5)  CE_A(K2,K6)  CE_A(K3,K7)
  CE_A(K8,K12) CE_A(K9,K13) CE_A(K10,K14) CE_A(K11,K15)
  CE_A(K0,K2)  CE_A(K1,K3)  CE_A(K4,K6)  CE_A(K5,K7)
  CE_A(K8,K10) CE_A(K9,K11) CE_A(K12,K14) CE_A(K13,K15)
  CE_A(K0,K1)  CE_A(K2,K3)  CE_A(K4,K5)  CE_A(K6,K7)
  CE_A(K8,K9)  CE_A(K10,K11) CE_A(K12,K13) CE_A(K14,K15)

  u64 out16 = ~0ULL;
  TOURNEY16(out16, lane)

  float B = __uint_as_float((unsigned)(__shfl(out16, KNN-1, 64) >> 32));
  const float thr = B*B + 2e-4f;

  const int qr = min(start + RW*32, NND);
  const int ql = max(start - RW*32, 0);
  bool ok;
  {
    bool rok = (qr >= NND);
    if (!rok){
      float xR = sxyid[qr-1].x;
      float dxr = ((float)bucketof(xR)*BW - 8.0f) - xi;
      rok = (dxr > 0.0f) && (dxr*dxr > thr);
    }
    bool lok = (ql <= 0);
    if (!lok){
      float xL = sxyid[ql].x;
      float dxl = xi - ((float)(bucketof(xL)+1)*BW - 8.0f);
      lok = (dxl > 0.0f) && (dxl*dxl > thr);
    }
    ok = rok && lok;
  }
  if (lane == 0 && !ok){
    int s = atomicAdd(ocnt, 1);
    olist[s] = n;
    othr[s] = thr;
  }

  write_outputs(out16, lane, n, idx_out, w_out);
}

// ---------------- bounded rescan for deferred nodes ----------------
// r29-proven ladder + named-scalar proxy tournament (r37-proven).
__global__ __launch_bounds__(256, 4) void knn_ext_r38(
    const float4* __restrict__ sxyid,
    const float* __restrict__ cents, const int* __restrict__ offs,
    const int* __restrict__ olist, const float* __restrict__ othr,
    const int* __restrict__ ocnt,
    int* __restrict__ idx_out, float* __restrict__ w_out)
{
  __shared__ u64 merged[64];         // 4 waves x 16 survivors
  const int lane = threadIdx.x & 63, wv = threadIdx.x >> 6;
  const int cnt = *ocnt;

  for (int slot = blockIdx.x; slot < cnt; slot += gridDim.x){
    const int n = olist[slot];
    const float thr = othr[slot];
    const float rB = __fsqrt_rn(thr) * (1.0f + 2e-6f);
    const float xi = cents[2*n];
    const float yi = cents[2*n+1];
    float sx = xi*xi; FPBAR(sx);
    float sy = yi*yi; FPBAR(sy);
    float sqi = sx + sy; FPBAR(sqi);

    const int bL = bucketof(xi - rB);
    const int bR = bucketof(xi + rB);
    const int posL = offs[bL];
    const int posR = (bR + 1 < NB) ? offs[bR + 1] : NND;

    u64 L[KNN];
    #pragma unroll
    for (int t=0;t<KNN;t++) L[t] = ~0ULL;

    int p = posL + (wv<<6) + lane;
    for (; p + 256 < posR; p += 512){
      float4 c0 = sxyid[p];
      float4 c1 = sxyid[p+256];
      u64 k0 = make_key(xi, yi, sqi, c0.x, c0.y, __float_as_int(c0.z), n);
      u64 k1 = make_key(xi, yi, sqi, c1.x, c1.y, __float_as_int(c1.z), n);
      if (k0 < L[KNN-1]) ladder_insert(L, k0);   // exact: key>=L[15] is a no-op
      if (k1 < L[KNN-1]) ladder_insert(L, k1);
    }
    if (p < posR){
      float4 c0 = sxyid[p];
      u64 k0 = make_key(xi, yi, sqi, c0.x, c0.y, __float_as_int(c0.z), n);
      if (k0 < L[KNN-1]) ladder_insert(L, k0);
    }

    // copy to named scalars (static) -> spill-proof tournament
    u64 K0=L[0], K1=L[1], K2=L[2],  K3=L[3],  K4=L[4],  K5=L[5],  K6=L[6],  K7=L[7],
        K8=L[8], K9=L[9], K10=L[10],K11=L[11],K12=L[12],K13=L[13],K14=L[14],K15=L[15];
    u64 w16 = ~0ULL;
    TOURNEY16(w16, lane)

    if (lane < KNN) merged[(wv<<4) + lane] = w16;
    __syncthreads();
    if (wv == 0){
      u64 out16 = merge64(merged, lane);
      write_outputs(out16, lane, n, idx_out, w_out);
    }
    __syncthreads();   // merged[] reused next slot
  }
}

// ---------------- GEMM: W-in-LDS (depth-2 prefetch) + A-in-registers ----------------
// r30-proven. Used for the two DUAL sage GEMMs.
template<int OUT, bool DUAL, bool BIAS, bool SPLITOUT>
__global__ __launch_bounds__(256, 4) void mm_mfma_r38(
    const unsigned short* __restrict__ A1h, const unsigned short* __restrict__ A1l,
    const unsigned short* __restrict__ A2h, const unsigned short* __restrict__ A2l,
    const unsigned short* __restrict__ W1h, const unsigned short* __restrict__ W1l,
    const unsigned short* __restrict__ W2h, const unsigned short* __restrict__ W2l,
    const float* __restrict__ bias,
    float* __restrict__ Cf, unsigned short* __restrict__ Ch, unsigned short* __restrict__ Cl)
{
  constexpr int NTILW = DUAL ? 4 : 2;      // W tiles per k-step
  constexpr int NW  = DUAL ? 4 : 2;        // W gload_lds per wave per step
  constexpr int NA  = DUAL ? 4 : 2;        // A register loads per lane per step
  constexpr int NCG = OUT / 64;            // 4 or 2
  constexpr int LG  = (NCG == 4) ? 2 : 1;
  constexpr int RTM = (NND + 63) / 64;     // 188
  __shared__ unsigned short sbW[3][NTILW][2048];   // 3 buffers x W tiles x 4KB
  const int lane = threadIdx.x & 63, wv = threadIdx.x >> 6;
  const int bid = blockIdx.x;
  const int xcd = bid & 7;
  const int cg  = (bid >> 3) & (NCG - 1);
  const int rt  = ((bid >> (3 + LG)) << 3) + xcd;
  if (rt >= RTM) return;
  const int row0 = rt*64;
  const int n0 = cg*64;
  const int l15 = lane & 15;
  const int quad = lane >> 4;

  const size_t woff = (size_t)(n0 + lane) * DM;
  const unsigned short* wsrc;
  int wtile, q0;
  if (DUAL){
    wsrc = ((wv==0) ? W1h : (wv==1) ? W1l : (wv==2) ? W2h : W2l) + woff;
    wtile = wv; q0 = 0;
  } else {
    wsrc = ((wv < 2) ? W1h : W1l) + woff;
    wtile = wv >> 1; q0 = (wv & 1) * 2;
  }

  const int am = min(row0 + wv*16 + l15, NND-1);
  const size_t abase = (size_t)am*DM + quad*8;

  f4_t acc[4];
  #pragma unroll
  for (int t=0;t<4;t++) acc[t] = (f4_t){0.f,0.f,0.f,0.f};

  bf8_t A1H[3], A1L[3], A2H[3], A2L[3];

  auto STAGE = [&](int b, int ks){
    if (DUAL){
      #pragma unroll
      for (int j=0;j<4;j++)
        gload16(wsrc + ks*32 + j*8, &sbW[b][wtile][j*512]);
    } else {
      #pragma unroll
      for (int j=0;j<2;j++)
        gload16(wsrc + ks*32 + (q0+j)*8, &sbW[b][wtile][(q0+j)*512]);
    }
  };
  auto LOADA = [&](int s, int ks){
    A1H[s] = *(const bf8_t*)(A1h + abase + ks*32);
    A1L[s] = *(const bf8_t*)(A1l + abase + ks*32);
    if (DUAL){
      A2H[s] = *(const bf8_t*)(A2h + abase + ks*32);
      A2L[s] = *(const bf8_t*)(A2l + abase + ks*32);
    }
  };

  STAGE(0, 0); LOADA(0, 0);
  STAGE(1, 1); LOADA(1, 1);
  constexpr int NKS = DM/32;             // 8
  #pragma unroll
  for (int ks=0; ks<NKS; ++ks){
    const int b = ks % 3;
    if (ks + 2 < NKS){ STAGE((ks+2)%3, ks+2); LOADA((ks+2)%3, ks+2); }
    if (ks + 2 < NKS)      asm volatile("s_waitcnt vmcnt(%0)" :: "i"(2*(NW+NA)) : "memory");
    else if (ks + 1 < NKS) asm volatile("s_waitcnt vmcnt(%0)" :: "i"(NW+NA) : "memory");
    else                   asm volatile("s_waitcnt vmcnt(0)" ::: "memory");
    __builtin_amdgcn_sched_barrier(0);
    __builtin_amdgcn_s_barrier();        // all waves: W tiles for ks complete
    __builtin_amdgcn_sched_barrier(0);
    {
      bf8_t a1h = A1H[b], a1l = A1L[b];
      bf8_t a2h, a2l;
      if (DUAL){ a2h = A2H[b]; a2l = A2L[b]; }
      #pragma unroll
      for (int t=0;t<4;t++){
        const int wr = quad*512 + (t*16 + l15)*8;
        bf8_t bh = *(const bf8_t*)&sbW[b][0][wr];
        bf8_t bl = *(const bf8_t*)&sbW[b][1][wr];
        acc[t] = __builtin_amdgcn_mfma_f32_16x16x32_bf16(a1h, bh, acc[t], 0, 0, 0);
        acc[t] = __builtin_amdgcn_mfma_f32_16x16x32_bf16(a1h, bl, acc[t], 0, 0, 0);
        acc[t] = __builtin_amdgcn_mfma_f32_16x16x32_bf16(a1l, bh, acc[t], 0, 0, 0);
        if (DUAL){
          bf8_t ch = *(const bf8_t*)&sbW[b][2][wr];
          bf8_t cl = *(const bf8_t*)&sbW[b][3][wr];
          acc[t] = __builtin_amdgcn_mfma_f32_16x16x32_bf16(a2h, ch, acc[t], 0, 0, 0);
          acc[t] = __builtin_amdgcn_mfma_f32_16x16x32_bf16(a2h, cl, acc[t], 0, 0, 0);
          acc[t] = __builtin_amdgcn_mfma_f32_16x16x32_bf16(a2l, ch, acc[t], 0, 0, 0);
        }
      }
    }
    __builtin_amdgcn_sched_barrier(0);
    asm volatile("s_waitcnt lgkmcnt(0)" ::: "memory");
    __builtin_amdgcn_s_barrier();        // all waves done reading buffer b
    __builtin_amdgcn_sched_barrier(0);
  }

  #pragma unroll
  for (int t=0;t<4;t++){
    int n = n0 + t*16 + l15;
    float bv = BIAS ? bias[n] : 0.f;
    #pragma unroll
    for (int r=0;r<4;r++){
      int row = row0 + wv*16 + quad*4 + r;
      if (row < NND){
        float v = geluf(acc[t][r] + bv);
        if (SPLITOUT){
          unsigned short hb = bf16_rne(v);
          float hf = __uint_as_float(((unsigned)hb) << 16);
          Ch[(size_t)row*OUT + n] = hb;
          Cl[(size_t)row*OUT + n] = bf16_rne(v - hf);
        } else {
          Cf[(size_t)row*OUT + n] = v;
        }
      }
    }
  }
}

// ---------------- CLASSIFIER: full-row GEMM + fused cls2 dot (r35-proven) ----------------
__global__ __launch_bounds__(256, 4) void cls_fused_r38(
    const unsigned short* __restrict__ A1h, const unsigned short* __restrict__ A1l,
    const unsigned short* __restrict__ W1h, const unsigned short* __restrict__ W1l,
    const float* __restrict__ bias, const float* __restrict__ w2,
    const float* __restrict__ b2,
    void* __restrict__ out, const int* __restrict__ flag)
{
  constexpr int NW = 4, NA = 2;            // vm ops per wave per step
  constexpr int RTM = (NND + 63) / 64;     // 188
  __shared__ unsigned short sbW[3][2][4096];   // 3 buf x {h,l} x 8KB (48KB)
  const int lane = threadIdx.x & 63, wv = threadIdx.x >> 6;
  const int bid = blockIdx.x;
  const int xcd = bid & 7;
  const int rt  = ((bid >> 3) << 3) + xcd;
  if (rt >= RTM) return;
  const int row0 = rt*64;
  const int l15 = lane & 15;
  const int quad = lane >> 4;

  const int am = min(row0 + wv*16 + l15, NND-1);
  const size_t abase = (size_t)am*DM + quad*8;

  f4_t acc[8];
  #pragma unroll
  for (int t=0;t<8;t++) acc[t] = (f4_t){0.f,0.f,0.f,0.f};

  bf8_t A1H[3], A1L[3];

  auto STAGE = [&](int b, int ks){
    #pragma unroll
    for (int j=0;j<4;j++){
      const int g = wv*4 + j;
      const int a = g >> 3, rem = g & 7, q = rem >> 1, half = rem & 1;
      const unsigned short* ws = (a ? W1l : W1h)
          + (size_t)(half*64 + lane)*DM + ks*32 + q*8;
      gload16(ws, &sbW[b][a][q*1024 + half*512]);
    }
  };
  auto LOADA = [&](int s, int ks){
    A1H[s] = *(const bf8_t*)(A1h + abase + ks*32);
    A1L[s] = *(const bf8_t*)(A1l + abase + ks*32);
  };

  STAGE(0, 0); LOADA(0, 0);
  STAGE(1, 1); LOADA(1, 1);
  constexpr int NKS = DM/32;             // 8
  #pragma unroll
  for (int ks=0; ks<NKS; ++ks){
    const int b = ks % 3;
    if (ks + 2 < NKS){ STAGE((ks+2)%3, ks+2); LOADA((ks+2)%3, ks+2); }
    if (ks + 2 < NKS)      asm volatile("s_waitcnt vmcnt(%0)" :: "i"(2*(NW+NA)) : "memory");
    else if (ks + 1 < NKS) asm volatile("s_waitcnt vmcnt(%0)" :: "i"(NW+NA) : "memory");
    else                   asm volatile("s_waitcnt vmcnt(0)" ::: "memory");
    __builtin_amdgcn_sched_barrier(0);
    __builtin_amdgcn_s_barrier();
    __builtin_amdgcn_sched_barrier(0);
    {
      bf8_t a1h = A1H[b], a1l = A1L[b];
      #pragma unroll
      for (int t=0;t<8;t++){
        const int wr = quad*1024 + (t*16 + l15)*8;
        bf8_t bh = *(const bf8_t*)&sbW[b][0][wr];
        bf8_t bl = *(const bf8_t*)&sbW[b][1][wr];
        acc[t] = __builtin_amdgcn_mfma_f32_16x16x32_bf16(a1h, bh, acc[t], 0, 0, 0);
        acc[t] = __builtin_amdgcn_mfma_f32_16x16x32_bf16(a1h, bl, acc[t], 0, 0, 0);
        acc[t] = __builtin_amdgcn_mfma_f32_16x16x32_bf16(a1l, bh, acc[t], 0, 0, 0);
      }
    }
    __builtin_amdgcn_sched_barrier(0);
    asm volatile("s_waitcnt lgkmcnt(0)" ::: "memory");
    __builtin_amdgcn_s_barrier();
    __builtin_amdgcn_sched_barrier(0);
  }

  // epilogue: gelu + dot(w2) + 16-lane reduce + sigmoid -> out
  const int is_bf16 = *flag;
  float partial0=0.f, partial1=0.f, partial2=0.f, partial3=0.f;
  #pragma unroll
  for (int t=0;t<8;t++){
    const int c = t*16 + l15;
    const float bv = bias[c];
    const float wc = w2[c];
    partial0 = fmaf(geluf(acc[t][0] + bv), wc, partial0);
    partial1 = fmaf(geluf(acc[t][1] + bv), wc, partial1);
    partial2 = fmaf(geluf(acc[t][2] + bv), wc, partial2);
    partial3 = fmaf(geluf(acc[t][3] + bv), wc, partial3);
  }
  #pragma unroll
  for (int o=1; o<16; o<<=1){
    partial0 += __shfl_xor(partial0, o, 64);
    partial1 += __shfl_xor(partial1, o, 64);
    partial2 += __shfl_xor(partial2, o, 64);
    partial3 += __shfl_xor(partial3, o, 64);
  }
  if (l15 == 0){
    const float bb = b2[0];
    #pragma unroll
    for (int r=0;r<4;r++){
      float s = (r==0)?partial0:(r==1)?partial1:(r==2)?partial2:partial3;
      int row = row0 + wv*16 + quad*4 + r;
      if (row < NND){
        float v = 1.0f / (1.0f + expf(-(s + bb)));
        if (is_bf16) ((__hip_bfloat16*)out)[row] = __float2bfloat16(v);
        else         ((float*)out)[row] = v;
      }
    }
  }
}

// ---------------- weighted neighbor aggregation ----------------
__global__ __launch_bounds__(256) void agg_kernel_r38(
    const unsigned short* __restrict__ hh, const unsigned short* __restrict__ hl,
    const int* __restrict__ idx, const float* __restrict__ w,
    unsigned short* __restrict__ oh, unsigned short* __restrict__ ol)
{
  const int lane = threadIdx.x & 63, wid = threadIdx.x >> 6;
  const int n = blockIdx.x*4 + wid;
  const int base = n*KNN;
  const int c = lane*4;
  float4 acc = make_float4(0.f,0.f,0.f,0.f);
  for (int k=0;k<KNN;k++){
    int j = idx[base+k];
    float wk = w[base+k];
    ushort4 vh = *(const ushort4*)(hh + (size_t)j*DM + c);
    ushort4 vl = *(const ushort4*)(hl + (size_t)j*DM + c);
    acc.x = fmaf(wk, bfpair(vh.x, vl.x), acc.x);
    acc.y = fmaf(wk, bfpair(vh.y, vl.y), acc.y);
    acc.z = fmaf(wk, bfpair(vh.z, vl.z), acc.z);
    acc.w = fmaf(wk, bfpair(vh.w, vl.w), acc.w);
  }
  unsigned short h0 = bf16_rne(acc.x); float f0 = __uint_as_float(((unsigned)h0) << 16);
  unsigned short h1 = bf16_rne(acc.y); float f1 = __uint_as_float(((unsigned)h1) << 16);
  unsigned short h2 = bf16_rne(acc.z); float f2 = __uint_as_float(((unsigned)h2) << 16);
  unsigned short h3 = bf16_rne(acc.w); float f3 = __uint_as_float(((unsigned)h3) << 16);
  ushort4 sh = make_ushort4(h0, h1, h2, h3);
  ushort4 sl = make_ushort4(bf16_rne(acc.x - f0), bf16_rne(acc.y - f1),
                            bf16_rne(acc.z - f2), bf16_rne(acc.w - f3));
  *(ushort4*)(oh + (size_t)n*DM + c) = sh;
  *(ushort4*)(ol + (size_t)n*DM + c) = sl;
}

// ---------------- h = h + layernorm(tmp)*g + b  (h stored as bf16 hi/lo) ----------------
__global__ __launch_bounds__(256) void ln_res_kernel_r38(
    unsigned short* __restrict__ hh, unsigned short* __restrict__ hl,
    const float* __restrict__ tmp, const float* __restrict__ g, const float* __restrict__ b)
{
  const int lane = threadIdx.x & 63, wid = threadIdx.x >> 6;
  const int n = blockIdx.x*4 + wid;
  float4 x = *(const float4*)(tmp + (size_t)n*DM + lane*4);
  float s = (x.x + x.y) + (x.z + x.w);
  #pragma unroll
  for (int off=32; off>0; off>>=1) s += __shfl_xor(s, off, 64);
  float mu = s * (1.0f/DM);
  float dx0 = x.x-mu, dx1 = x.y-mu, dx2 = x.z-mu, dx3 = x.w-mu;
  float v = (dx0*dx0 + dx1*dx1) + (dx2*dx2 + dx3*dx3);
  #pragma unroll
  for (int off=32; off>0; off>>=1) v += __shfl_xor(v, off, 64);
  float rs = 1.0f / sqrtf(v * (1.0f/DM) + 1e-5f);
  int c = lane*4;
  float4 gv = *(const float4*)(g + c);
  float4 bv = *(const float4*)(b + c);
  ushort4 vh = *(const ushort4*)(hh + (size_t)n*DM + c);
  ushort4 vl = *(const ushort4*)(hl + (size_t)n*DM + c);
  float o0 = bfpair(vh.x, vl.x) + dx0*rs*gv.x + bv.x;
  float o1 = bfpair(vh.y, vl.y) + dx1*rs*gv.y + bv.y;
  float o2 = bfpair(vh.z, vl.z) + dx2*rs*gv.z + bv.z;
  float o3 = bfpair(vh.w, vl.w) + dx3*rs*gv.w + bv.w;
  unsigned short h0 = bf16_rne(o0); float f0 = __uint_as_float(((unsigned)h0) << 16);
  unsigned short h1 = bf16_rne(o1); float f1 = __uint_as_float(((unsigned)h1) << 16);
  unsigned short h2 = bf16_rne(o2); float f2 = __uint_as_float(((unsigned)h2) << 16);
  unsigned short h3 = bf16_rne(o3); float f3 = __uint_as_float(((unsigned)h3) << 16);
  *(ushort4*)(hh + (size_t)n*DM + c) = make_ushort4(h0, h1, h2, h3);
  *(ushort4*)(hl + (size_t)n*DM + c) = make_ushort4(bf16_rne(o0 - f0), bf16_rne(o1 - f1),
                                                    bf16_rne(o2 - f2), bf16_rne(o3 - f3));
}

extern "C" void kernel_launch(void* const* d_in, const int* in_sizes, int n_in,
                              void* d_out, int out_size, void* d_ws, size_t ws_size,
                              hipStream_t stream)
{
  // ---- workspace layout (~46.6 MB), fully rewritten every call ----
  char* base = (char*)d_ws;
  int*   flag = (int*)base;                                   // 16 B slot
  float* wreg = (float*)(base + 16);
  static const int sizes[16] = {
    NND*256, NND*2, 256*256, 256, 256*256, 256*256, 256, 256,
    256*256, 256*256, 256, 256, 128*256, 128, 128, 1
  };
  float* ptrs[16];
  {
    float* p = wreg;
    for (int i = 2; i < 16; i++){ ptrs[i] = p; p += (sizes[i] + 3) & ~3; }
    ptrs[1] = p;                          // cents  [24,000]
    p += NND*2;
    ptrs[0] = p;                          // feats region  [3,072,000 floats]
  }
  float* F    = ptrs[0];                  // f32 tmp view of feats region
  unsigned short* fh = (unsigned short*)ptrs[0];          // feats hi
  unsigned short* fl = fh + (size_t)NND*DM;               // feats lo
  float* C    = ptrs[1];
  float* hbase = F + (size_t)NND*DM;
  unsigned short* h_hi = (unsigned short*)hbase;
  unsigned short* h_lo = h_hi + (size_t)NND*DM;
  float* abase = hbase + (size_t)NND*DM;
  unsigned short* a_hi = (unsigned short*)abase;
  unsigned short* a_lo = a_hi + (size_t)NND*DM;
  float* hid  = abase + (size_t)NND*DM;   // (region retained; cls2 fused away)
  int*  gidx  = (int*)(hid + (size_t)NND*128);
  float* gw   = (float*)(gidx + (size_t)NND*KNN);
  // knn pre-pass scratch (packed float4 candidates)
  float4* sxyid = (float4*)(gw + (size_t)NND*KNN);
  int*    hist  = (int*)(sxyid + NND);
  int*    cursor= hist + NB;
  int*    offs  = cursor + NB;
  int*    ocnt  = offs + NB;
  int*    olist = ocnt + 4;               // 16B pad keeps wh 16B-aligned
  float*  othr  = (float*)(olist + NND);  // thr per deferred node
  // bf16 hi/lo weights (enc_w | g1_ws | g1_wn | g2_ws | g2_wn | cls_w1), 16B-aligned
  unsigned short* wh = (unsigned short*)(((uintptr_t)(othr + NND) + 15) & ~(uintptr_t)15);
  unsigned short* wl = wh + NWELEM;

  // ---- dtype detect + decode (weights split to hi/lo IN decode; r34-proven) ----
  detect_kernel_r38<<<1, 256, 0, stream>>>((const unsigned*)d_in[1], 4096,
                                           (const unsigned*)d_in[0], 16384, flag);
  SegTable t;
  int total = 0;
  for (int i = 0; i < 16; i++){
    t.src[i] = d_in[i];
    t.dst[i] = ptrs[i];
    t.cnt[i] = sizes[i];
    t.wofs[i] = -1;
    total += sizes[i];
  }
  t.dst[0] = nullptr;       // feats handled via fh/fl
  t.wofs[2]  = 0;           // enc_w
  t.wofs[4]  = 65536;       // g1_ws
  t.wofs[5]  = 131072;      // g1_wn
  t.wofs[8]  = 196608;      // g2_ws
  t.wofs[9]  = 262144;      // g2_wn
  t.wofs[12] = 327680;      // cls_w1
  t.total = total;
  decode_kernel_r38<<<(total + 255)/256, 256, 0, stream>>>(t, fh, fl, wh, wl, flag);

  const float* enc_b  = ptrs[3];
  const float* g1_g   = ptrs[6];  const float* g1_b   = ptrs[7];
  const float* g2_g   = ptrs[10]; const float* g2_b   = ptrs[11];
  const float* cls_b1 = ptrs[13];
  const float* cls_w2 = ptrs[14]; const float* cls_b2 = ptrs[15];

  dim3 b256(256);
  // knn pre-pass: bucket counting sort by x (+ zero outlier counter)
  zero_kernel_r38<<<(NB + 255)/256, b256, 0, stream>>>(hist, cursor, ocnt);
  count_kernel_r38<<<(NND + 255)/256, b256, 0, stream>>>(C, hist);
  scan_kernel_r38<<<1, 1024, 0, stream>>>(hist, offs);
  scatter_kernel_r38<<<(NND + 255)/256, b256, 0, stream>>>(C, offs, cursor, sxyid);
  // swizzled grids: 24 rt-groups of 8 XCD-slots x NCG col-groups
  const int G4 = 24 * 8 * 4;   // 768  (OUT=256)
  // FUSED: knn_fixed (blocks 0..2999) || encoder GEMM (blocks 3000..3767)
  fused_enc_knn_r38<<<KBLK + G4, b256, 0, stream>>>(
      fh, fl, wh + 0, wl + 0, enc_b, h_hi, h_lo,
      sxyid, C, offs, gidx, gw, ocnt, olist, othr);
  knn_ext_r38<<<2048, b256, 0, stream>>>(sxyid, C, offs, olist, othr, ocnt, gidx, gw);
  // sage layer 1 (tmp := F region, feats dead after encoder)
  agg_kernel_r38<<<NND/4, b256, 0, stream>>>(h_hi, h_lo, gidx, gw, a_hi, a_lo);
  mm_mfma_r38<256,true,false,false><<<G4, b256, 0, stream>>>(h_hi, h_lo, a_hi, a_lo,
      wh + 65536, wl + 65536, wh + 131072, wl + 131072, nullptr, F, nullptr, nullptr);
  ln_res_kernel_r38<<<NND/4, b256, 0, stream>>>(h_hi, h_lo, F, g1_g, g1_b);
  // sage layer 2
  agg_kernel_r38<<<NND/4, b256, 0, stream>>>(h_hi, h_lo, gidx, gw, a_hi, a_lo);
  mm_mfma_r38<256,true,false,false><<<G4, b256, 0, stream>>>(h_hi, h_lo, a_hi, a_lo,
      wh + 196608, wl + 196608, wh + 262144, wl + 262144, nullptr, F, nullptr, nullptr);
  ln_res_kernel_r38<<<NND/4, b256, 0, stream>>>(h_hi, h_lo, F, g2_g, g2_b);
  // classifier: full-row GEMM + fused cls2 dot -> d_out (192 blocks)
  cls_fused_r38<<<24*8, b256, 0, stream>>>(h_hi, h_lo,
      wh + 327680, wl + 327680, cls_b1, cls_w2, cls_b2, d_out, flag);
}

// Round 21
// 362.487 us; speedup vs baseline: 1.0380x; 1.0030x over previous
//
#include <hip/hip_runtime.h>
#include <hip/hip_bf16.h>
#include <stdint.h>

#define NND 12000
#define DM  256
#define KNN 16
#define NB  4096          // x-buckets
#define BW  0.00390625f   // bucket width = 1/256 over [-8, 8)
#define RW  16            // fixed-window rounds (16*64 = 1024 candidates)
#define NWELEM 360448     // total weight elements converted to bf16 hi/lo
#define KBLK (NND/4)      // 3000 knn blocks first (r32 ordering, measured best)

// Opaque register barrier: prevents FMA contraction (r9: made knn bit-match numpy
// -> absmax 0.0. DO NOT REMOVE from knn path).
#define FPBAR(x) asm volatile("" : "+v"(x))

typedef unsigned long long u64;
typedef __attribute__((ext_vector_type(8))) short bf8_t;   // 8 bf16 (4 VGPRs)
typedef __attribute__((ext_vector_type(4))) float f4_t;

__device__ __forceinline__ float geluf(float x){ return 0.5f*x*(1.0f + erff(x*0.70710678118654752f)); }
__device__ __forceinline__ int bucketof(float x){
  int b = (int)floorf((x + 8.0f) * 256.0f);
  return min(max(b, 0), NB-1);
}

__device__ __forceinline__ unsigned short bf16_rne(float x){
  unsigned u = __float_as_uint(x);
  unsigned r = u + 0x7FFF + ((u >> 16) & 1);
  return (unsigned short)(r >> 16);
}

__device__ __forceinline__ float bfpair(unsigned short h, unsigned short l){
  return __uint_as_float(((unsigned)h) << 16) + __uint_as_float(((unsigned)l) << 16);
}

// async global->LDS, 16B per lane. LDS dest is WAVE-UNIFORM base + lane*16;
// global src is per-lane. Completion tracked by vmcnt.
__device__ __forceinline__ void gload16(const unsigned short* g, unsigned short* l){
  __builtin_amdgcn_global_load_lds(
      (__attribute__((address_space(1))) void*)g,
      (__attribute__((address_space(3))) void*)l, 16, 0, 0);
}

// bit-exact numpy distance key (r9-verified). Low 32 bits = original node idx.
__device__ __forceinline__ u64 make_key(float xi, float yi, float sqi,
                                        float cx, float cy, int jd, int self){
  float ax = cx*cx;  FPBAR(ax);
  float ay = cy*cy;  FPBAR(ay);
  float sqj = ax + ay;   FPBAR(sqj);
  float px = xi*cx;    FPBAR(px);
  float py = yi*cy;    FPBAR(py);
  float dt = px + py;    FPBAR(dt);            // NO-FMA dot
  float two_dt = 2.0f*dt;  FPBAR(two_dt);
  float ss = sqi + sqj;    FPBAR(ss);
  float d2 = ss - two_dt;  FPBAR(d2);
  float dist = __fsqrt_rn(fmaxf(d2, 0.0f));
  u64 key = ((u64)__float_as_uint(dist) << 32) | (unsigned)jd;
  return (jd == self) ? ~0ULL : key;
}

__device__ __forceinline__ void ladder_insert(u64* L, u64 key){
  bool c[KNN];
  #pragma unroll
  for (int t=0;t<KNN;t++) c[t] = key < L[t];
  #pragma unroll
  for (int t=KNN-1;t>=1;t--) L[t] = c[t-1] ? L[t-1] : (c[t] ? key : L[t]);
  L[0] = c[0] ? key : L[0];
}

// merge 64 candidate keys (one per lane) -> lane r holds r-th smallest (r<16).
__device__ __forceinline__ u64 merge64(const u64* m, int lane)
{
  u64 cur = m[lane];
  u64 out16 = ~0ULL;
  for (int r=0;r<KNN;r++){
    u64 k = cur; int who = lane;
    #pragma unroll
    for (int o=32;o>0;o>>=1){
      u64 ok = __shfl_xor(k, o, 64);
      int ow = __shfl_xor(who, o, 64);
      if (ok < k){ k = ok; who = ow; }
    }
    if (lane == r) out16 = k;
    if (lane == who) cur = ~0ULL;
  }
  return out16;
}

// r39: one division per lane + commutative-tree shfl reduce. Lane t (t<16)
// holds the t-th smallest key; the xor-{8,1,2,4} reduce reproduces the old
// pinned tree ((i0+i8)+(i1+i9))+((i2+i10)+(i3+i11)) ... BITWISE (IEEE add is
// commutative in result bits; offsets <16 keep each 16-lane group closed).
// Sentinel lanes (>=16 or padding) produce garbage in their own group only
// and never write. Saves 15 fdivs + 16 broadcast shfls per node.
__device__ __forceinline__ void write_outputs(u64 out16, int lane, int n,
    int* __restrict__ idx_out, float* __restrict__ w_out)
{
  if (lane < KNN) idx_out[(size_t)n*KNN + lane] = (int)(unsigned)(out16 & 0xFFFFFFFFull);
  float d = __uint_as_float((unsigned)(out16 >> 32));
  float invL = __fdiv_rn(1.0f, fmaxf(d, 1e-4f));
  float s = invL;
  s += __shfl_xor(s, 8, 64);  FPBAR(s);   // i[t] + i[t+8]   (= r8v)
  s += __shfl_xor(s, 1, 64);  FPBAR(s);   // r8v pairs       (= s01/s23/...)
  s += __shfl_xor(s, 2, 64);  FPBAR(s);   // (= sA/sB)
  s += __shfl_xor(s, 4, 64);  FPBAR(s);   // (= sA + sB)
  s = fmaxf(s, 1e-8f);
  if (lane < KNN){
    w_out[(size_t)n*KNN + lane] = __fdiv_rn(invL, s);
  }
}

// compare-exchange macro (ascending). Named scalars only — r20/r28 lesson:
// u64 ARRAYS mutated through pointers/under exec-mask get lowered to scratch.
#define CE_A(x,y) { u64 mn_=(x)<(y)?(x):(y); u64 mx_=(x)<(y)?(y):(x); (x)=mn_; (y)=mx_; }

// r36-proven: EXACT wave-min of 64 head keys via 32-bit DISTANCE-PROXY
// butterfly. Key = (dist_bits<<32)|idx with positive-float dist -> min dist
// via u32 v_min butterfly (half the u64 cost). Single-match fast path is the
// exact u64 min; ties (wave-uniform rare branch) fall back to full u64
// butterfly. Bit-exact incl. all-sentinel rounds (tie path, who=ffs=0).
#define PSELECT(k, who, cur, curd) {                                \
    unsigned d_ = curd;                                             \
    _Pragma("unroll")                                               \
    for (int o_=32;o_>0;o_>>=1){                                    \
      unsigned od_ = __shfl_xor(d_, o_, 64);                        \
      d_ = min(d_, od_);                                            \
    }                                                               \
    u64 ball_ = __ballot(curd == d_);                               \
    if (ball_ & (ball_ - 1)){                                       \
      u64 c2_ = (curd == d_) ? cur : ~0ULL;                         \
      _Pragma("unroll")                                             \
      for (int o_=32;o_>0;o_>>=1){                                  \
        u64 oc_ = __shfl_xor(c2_, o_, 64);                          \
        if (oc_ < c2_) c2_ = oc_;                                   \
      }                                                             \
      k = c2_;                                                      \
      who = __ffsll(__ballot(cur == k)) - 1;                        \
    } else {                                                        \
      who = __ffsll(ball_) - 1;                                     \
      k = __shfl(cur, who, 64);                                     \
    }                                                               \
  }

// r39: proxy tournament with p-INDEXED refill. Winner tracks its win count
// p_ and selects the next head: shallow chain (p_<4, the common case) costs
// ~6 VALU; the deep chain sits behind an exec-masked branch reached only
// when one lane has won >=4 rounds. Same selection sequence as the r38
// shift refill -> bit-identical output. Worst case (full if-conversion)
// equals the old 30-mov shift; best case saves ~350 issued ops.
#define TOURNEY16(out16, lane) {                                   \
    u64 cur = K0; unsigned curd = (unsigned)(cur >> 32);           \
    int p_ = 0;                                                    \
    for (int r_=0;r_<KNN;r_++){                                    \
      u64 k_; int who_;                                            \
      PSELECT(k_, who_, cur, curd)                                 \
      if ((lane) == r_) out16 = k_;                                \
      if ((lane) == who_){                                         \
        ++p_;                                                      \
        u64 nxt_;                                                  \
        if (p_ < 4){                                               \
          nxt_ = (p_==1)?K1:(p_==2)?K2:K3;                         \
        } else {                                                   \
          nxt_ = (p_==4)?K4:(p_==5)?K5:(p_==6)?K6:(p_==7)?K7:      \
                 (p_==8)?K8:(p_==9)?K9:(p_==10)?K10:(p_==11)?K11:  \
                 (p_==12)?K12:(p_==13)?K13:(p_==14)?K14:           \
                 (p_==15)?K15:~0ULL;                               \
        }                                                          \
        cur = nxt_; curd = (unsigned)(nxt_ >> 32);                 \
      }                                                            \
    }                                                              \
  }

// ---------------- dtype detection (proven: picks f32 here) ----------------
__global__ __launch_bounds__(256) void detect_kernel_r39(
    const unsigned* __restrict__ a, int na,
    const unsigned* __restrict__ b, int nb, int* __restrict__ flag)
{
  __shared__ int cnt;
  if (threadIdx.x == 0) cnt = 0;
  __syncthreads();
  int c = 0;
  for (int i = threadIdx.x; i < na; i += 256){
    int ex = (a[i] >> 7) & 0xFF;
    c += (ex >= 113 && ex <= 131) ? 1 : 0;
  }
  for (int i = threadIdx.x; i < nb; i += 256){
    int ex = (b[i] >> 7) & 0xFF;
    c += (ex >= 113 && ex <= 131) ? 1 : 0;
  }
  atomicAdd(&cnt, c);
  __syncthreads();
  if (threadIdx.x == 0) *flag = (cnt > (na + nb) / 2) ? 1 : 0;
}

// ---------------- decode all inputs (fused weight hi/lo split; r34-proven) ----------------
struct SegTable {
  const void* src[16];
  float*      dst[16];
  int         cnt[16];
  int         wofs[16];   // >=0: offset into wh/wl for weight segs, else -1
  int         total;
};

__global__ __launch_bounds__(256) void decode_kernel_r39(SegTable t,
    unsigned short* __restrict__ fh, unsigned short* __restrict__ fl,
    unsigned short* __restrict__ dh, unsigned short* __restrict__ dl,
    const int* __restrict__ flag)
{
  const int is_bf16 = *flag;
  for (int e = blockIdx.x*256 + threadIdx.x; e < t.total; e += gridDim.x*256){
    int rem = e, s = 0;
    while (rem >= t.cnt[s]){ rem -= t.cnt[s]; ++s; }
    float v;
    if (is_bf16) v = __uint_as_float(((unsigned)((const unsigned short*)t.src[s])[rem]) << 16);
    else         v = ((const float*)t.src[s])[rem];
    if (s == 0){
      unsigned short hb = bf16_rne(v);
      float hf = __uint_as_float(((unsigned)hb) << 16);
      fh[rem] = hb;
      fl[rem] = bf16_rne(v - hf);
    } else {
      int wo = t.wofs[s];
      if (wo >= 0){
        unsigned short hb = bf16_rne(v);
        float hf = __uint_as_float(((unsigned)hb) << 16);
        dh[wo + rem] = hb;
        dl[wo + rem] = bf16_rne(v - hf);
      } else {
        t.dst[s][rem] = v;
      }
    }
  }
}

// ---------------- bucket pre-pass ----------------
__global__ __launch_bounds__(256) void zero_kernel_r39(int* __restrict__ hist, int* __restrict__ cursor,
                                                       int* __restrict__ ocnt)
{
  int t = blockIdx.x*256 + threadIdx.x;
  if (t < NB){ hist[t] = 0; cursor[t] = 0; }
  if (blockIdx.x == 0 && threadIdx.x == 0) *ocnt = 0;
}

__global__ __launch_bounds__(256) void count_kernel_r39(const float* __restrict__ cents,
                                                        int* __restrict__ hist)
{
  int i = blockIdx.x*256 + threadIdx.x;
  if (i < NND) atomicAdd(&hist[bucketof(cents[2*i])], 1);
}

__global__ __launch_bounds__(1024) void scan_kernel_r39(const int* __restrict__ hist,
                                                        int* __restrict__ offs)
{
  __shared__ int s[1024];
  int t = threadIdx.x;
  int h0 = hist[t*4], h1 = hist[t*4+1], h2 = hist[t*4+2], h3 = hist[t*4+3];
  int tot = h0+h1+h2+h3;
  s[t] = tot;
  __syncthreads();
  for (int d=1; d<1024; d<<=1){
    int v = (t >= d) ? s[t-d] : 0;
    __syncthreads();
    s[t] += v;
    __syncthreads();
  }
  int excl = s[t] - tot;
  offs[t*4]   = excl;
  offs[t*4+1] = excl + h0;
  offs[t*4+2] = excl + h0 + h1;
  offs[t*4+3] = excl + h0 + h1 + h2;
}

// scatter packs (x, y, bitcast(id)) into ONE float4 (r35-proven).
__global__ __launch_bounds__(256) void scatter_kernel_r39(const float* __restrict__ cents,
    const int* __restrict__ offs, int* __restrict__ cursor,
    float4* __restrict__ sxyid)
{
  int i = blockIdx.x*256 + threadIdx.x;
  if (i < NND){
    float x = cents[2*i], y = cents[2*i+1];
    int b = bucketof(x);
    int pos = offs[b] + atomicAdd(&cursor[b], 1);
    sxyid[pos] = make_float4(x, y, __int_as_float(i), 0.f);
  }
}

// ---------------- FUSED: encoder GEMM (blocks >= KBLK) || knn_fixed (blocks < KBLK) ----------------
// r32-proven structure; r39: Batcher merge-exchange (63 ascending CE, vs 80
// bitonic) + p-indexed tournament refill + 1-div write_outputs. Identical
// sorted order + identical selection sequence -> bit-identical outputs.
__global__ __launch_bounds__(256, 4) void fused_enc_knn_r39(
    // encoder args
    const unsigned short* __restrict__ A1h, const unsigned short* __restrict__ A1l,
    const unsigned short* __restrict__ W1h, const unsigned short* __restrict__ W1l,
    const float* __restrict__ bias,
    unsigned short* __restrict__ Ch, unsigned short* __restrict__ Cl,
    // knn args
    const float4* __restrict__ sxyid,
    const float* __restrict__ cents, const int* __restrict__ offs,
    int* __restrict__ idx_out, float* __restrict__ w_out,
    int* __restrict__ ocnt, int* __restrict__ olist, float* __restrict__ othr)
{
  __shared__ unsigned short sbW[3][2][2048];   // 24KB, encoder path only
  const int lane = threadIdx.x & 63, wv = threadIdx.x >> 6;

  if (blockIdx.x >= KBLK){
    // ================= encoder body (mm_mfma_r30 <256,false,true,true>) ===========
    constexpr int NW = 2, NA = 2;
    constexpr int NCG = 4, LG = 2;
    constexpr int RTM = (NND + 63) / 64;   // 188
    const int ebid = blockIdx.x - KBLK;
    const int xcd = ebid & 7;
    const int cg  = (ebid >> 3) & (NCG - 1);
    const int rt  = ((ebid >> (3 + LG)) << 3) + xcd;
    if (rt >= RTM) return;
    const int row0 = rt*64;
    const int n0 = cg*64;
    const int l15 = lane & 15;
    const int quad = lane >> 4;

    const size_t woff = (size_t)(n0 + lane) * DM;
    const unsigned short* wsrc = ((wv < 2) ? W1h : W1l) + woff;
    const int wtile = wv >> 1, q0 = (wv & 1) * 2;

    const int am = min(row0 + wv*16 + l15, NND-1);
    const size_t abase = (size_t)am*DM + quad*8;

    f4_t acc[4];
    #pragma unroll
    for (int t=0;t<4;t++) acc[t] = (f4_t){0.f,0.f,0.f,0.f};

    bf8_t A1H[3], A1L[3];

    auto STAGE = [&](int b, int ks){
      #pragma unroll
      for (int j=0;j<2;j++)
        gload16(wsrc + ks*32 + (q0+j)*8, &sbW[b][wtile][(q0+j)*512]);
    };
    auto LOADA = [&](int s, int ks){
      A1H[s] = *(const bf8_t*)(A1h + abase + ks*32);
      A1L[s] = *(const bf8_t*)(A1l + abase + ks*32);
    };

    STAGE(0, 0); LOADA(0, 0);
    STAGE(1, 1); LOADA(1, 1);
    constexpr int NKS = DM/32;             // 8
    #pragma unroll
    for (int ks=0; ks<NKS; ++ks){
      const int b = ks % 3;
      if (ks + 2 < NKS){ STAGE((ks+2)%3, ks+2); LOADA((ks+2)%3, ks+2); }
      if (ks + 2 < NKS)      asm volatile("s_waitcnt vmcnt(%0)" :: "i"(2*(NW+NA)) : "memory");
      else if (ks + 1 < NKS) asm volatile("s_waitcnt vmcnt(%0)" :: "i"(NW+NA) : "memory");
      else                   asm volatile("s_waitcnt vmcnt(0)" ::: "memory");
      __builtin_amdgcn_sched_barrier(0);
      __builtin_amdgcn_s_barrier();
      __builtin_amdgcn_sched_barrier(0);
      {
        bf8_t a1h = A1H[b], a1l = A1L[b];
        #pragma unroll
        for (int t=0;t<4;t++){
          const int wr = quad*512 + (t*16 + l15)*8;
          bf8_t bh = *(const bf8_t*)&sbW[b][0][wr];
          bf8_t bl = *(const bf8_t*)&sbW[b][1][wr];
          acc[t] = __builtin_amdgcn_mfma_f32_16x16x32_bf16(a1h, bh, acc[t], 0, 0, 0);
          acc[t] = __builtin_amdgcn_mfma_f32_16x16x32_bf16(a1h, bl, acc[t], 0, 0, 0);
          acc[t] = __builtin_amdgcn_mfma_f32_16x16x32_bf16(a1l, bh, acc[t], 0, 0, 0);
        }
      }
      __builtin_amdgcn_sched_barrier(0);
      asm volatile("s_waitcnt lgkmcnt(0)" ::: "memory");
      __builtin_amdgcn_s_barrier();
      __builtin_amdgcn_sched_barrier(0);
    }

    #pragma unroll
    for (int t=0;t<4;t++){
      int n = n0 + t*16 + l15;
      float bv = bias[n];
      #pragma unroll
      for (int r=0;r<4;r++){
        int row = row0 + wv*16 + quad*4 + r;
        if (row < NND){
          float v = geluf(acc[t][r] + bv);
          unsigned short hb = bf16_rne(v);
          float hf = __uint_as_float(((unsigned)hb) << 16);
          Ch[(size_t)row*DM + n] = hb;
          Cl[(size_t)row*DM + n] = bf16_rne(v - hf);
        }
      }
    }
    return;
  }

  // ================= knn_fixed body (packed float4 + proxy register tournament) =====
  const int n = blockIdx.x*4 + wv;
  const float xi = cents[2*n];
  const float yi = cents[2*n+1];
  float sx = xi*xi; FPBAR(sx);
  float sy = yi*yi; FPBAR(sy);
  float sqi = sx + sy; FPBAR(sqi);

  const int start = offs[bucketof(xi)];
  const bool isR = lane < 32;
  const int lo = isR ? lane : (lane - 32);

  u64 K0,K1,K2,K3,K4,K5,K6,K7,K8,K9,K10,K11,K12,K13,K14,K15;
  #define KROUND(r, K) { \
    int myp = isR ? (start + (r)*32 + lo) : (start - 1 - (r)*32 - lo); \
    bool act = (myp >= 0) && (myp < NND); \
    float4 cu = make_float4(0.f, 0.f, 0.f, 0.f); \
    int jd = -1; \
    if (act){ cu = sxyid[myp]; jd = __float_as_int(cu.z); } \
    u64 key = make_key(xi, yi, sqi, cu.x, cu.y, jd, n); \
    K = act ? key : ~0ULL; }
  KROUND(0,K0)   KROUND(1,K1)   KROUND(2,K2)   KROUND(3,K3)
  KROUND(4,K4)   KROUND(5,K5)   KROUND(6,K6)   KROUND(7,K7)
  KROUND(8,K8)   KROUND(9,K9)   KROUND(10,K10) KROUND(11,K11)
  KROUND(12,K12) KROUND(13,K13) KROUND(14,K14) KROUND(15,K15)
  #undef KROUND

  // Batcher merge-exchange sorting network, 16 keys ascending (63 CE, all
  // min-up). Full sort of distinct keys -> identical result to the old
  // 80-CE bitonic -> bit-identical downstream.
  // pass p=8
  CE_A(K0,K8)  CE_A(K1,K9)  CE_A(K2,K10) CE_A(K3,K11)
  CE_A(K4,K12) CE_A(K5,K13) CE_A(K6,K14) CE_A(K7,K15)
  // pass p=4
  CE_A(K0,K4)  CE_A(K1,K5)  CE_A(K2,K6)  CE_A(K3,K7)
  CE_A(K8,K12) CE_A(K9,K13) CE_A(K10,K14) CE_A(K11,K15)
  CE_A(K4,K8)  CE_A(K5,K9)  CE_A(K6,K10) CE_A(K7,K11)
  // pass p=2
  CE_A(K0,K2)  CE_A(K1,K3)  CE_A(K4,K6)  CE_A(K5,K7)
  CE_A(K8,K10) CE_A(K9,K11) CE_A(K12,K14) CE_A(K13,K15)
  CE_A(K2,K8)  CE_A(K3,K9)  CE_A(K6,K12) CE_A(K7,K13)
  CE_A(K2,K4)  CE_A(K3,K5)  CE_A(K6,K8)  CE_A(K7,K9)  CE_A(K10,K12) CE_A(K11,K13)
  // pass p=1
  CE_A(K0,K1)  CE_A(K2,K3)  CE_A(K4,K5)  CE_A(K6,K7)
  CE_A(K8,K9)  CE_A(K10,K11) CE_A(K12,K13) CE_A(K14,K15)
  CE_A(K1,K8)  CE_A(K3,K10) CE_A(K5,K12) CE_A(K7,K14)
  CE_A(K1,K4)  CE_A(K3,K6)  CE_A(K5,K8)  CE_A(K7,K10) CE_A(K9,K12) CE_A(K11,K14)
  CE_A(K1,K2)  CE_A(K3,K4)  CE_A(K5,K6)  CE_A(K7,K8)  CE_A(K9,K10) CE_A(K11,K12) CE_A(K13,K14)

  u64 out16 = ~0ULL;
  TOURNEY16(out16, lane)

  float B = __uint_as_float((unsigned)(__shfl(out16, KNN-1, 64) >> 32));
  const float thr = B*B + 2e-4f;

  const int qr = min(start + RW*32, NND);
  const int ql = max(start - RW*32, 0);
  bool ok;
  {
    bool rok = (qr >= NND);
    if (!rok){
      float xR = sxyid[qr-1].x;
      float dxr = ((float)bucketof(xR)*BW - 8.0f) - xi;
      rok = (dxr > 0.0f) && (dxr*dxr > thr);
    }
    bool lok = (ql <= 0);
    if (!lok){
      float xL = sxyid[ql].x;
      float dxl = xi - ((float)(bucketof(xL)+1)*BW - 8.0f);
      lok = (dxl > 0.0f) && (dxl*dxl > thr);
    }
    ok = rok && lok;
  }
  if (lane == 0 && !ok){
    int s = atomicAdd(ocnt, 1);
    olist[s] = n;
    othr[s] = thr;
  }

  write_outputs(out16, lane, n, idx_out, w_out);
}

// ---------------- bounded rescan for deferred nodes ----------------
// r29-proven ladder (keeps L[] sorted -> K0..K15 already ascending) +
// named-scalar proxy tournament with r39 p-indexed refill.
__global__ __launch_bounds__(256, 4) void knn_ext_r39(
    const float4* __restrict__ sxyid,
    const float* __restrict__ cents, const int* __restrict__ offs,
    const int* __restrict__ olist, const float* __restrict__ othr,
    const int* __restrict__ ocnt,
    int* __restrict__ idx_out, float* __restrict__ w_out)
{
  __shared__ u64 merged[64];         // 4 waves x 16 survivors
  const int lane = threadIdx.x & 63, wv = threadIdx.x >> 6;
  const int cnt = *ocnt;

  for (int slot = blockIdx.x; slot < cnt; slot += gridDim.x){
    const int n = olist[slot];
    const float thr = othr[slot];
    const float rB = __fsqrt_rn(thr) * (1.0f + 2e-6f);
    const float xi = cents[2*n];
    const float yi = cents[2*n+1];
    float sx = xi*xi; FPBAR(sx);
    float sy = yi*yi; FPBAR(sy);
    float sqi = sx + sy; FPBAR(sqi);

    const int bL = bucketof(xi - rB);
    const int bR = bucketof(xi + rB);
    const int posL = offs[bL];
    const int posR = (bR + 1 < NB) ? offs[bR + 1] : NND;

    u64 L[KNN];
    #pragma unroll
    for (int t=0;t<KNN;t++) L[t] = ~0ULL;

    int p = posL + (wv<<6) + lane;
    for (; p + 256 < posR; p += 512){
      float4 c0 = sxyid[p];
      float4 c1 = sxyid[p+256];
      u64 k0 = make_key(xi, yi, sqi, c0.x, c0.y, __float_as_int(c0.z), n);
      u64 k1 = make_key(xi, yi, sqi, c1.x, c1.y, __float_as_int(c1.z), n);
      if (k0 < L[KNN-1]) ladder_insert(L, k0);   // exact: key>=L[15] is a no-op
      if (k1 < L[KNN-1]) ladder_insert(L, k1);
    }
    if (p < posR){
      float4 c0 = sxyid[p];
      u64 k0 = make_key(xi, yi, sqi, c0.x, c0.y, __float_as_int(c0.z), n);
      if (k0 < L[KNN-1]) ladder_insert(L, k0);
    }

    // copy to named scalars (static) -> spill-proof tournament
    u64 K0=L[0], K1=L[1], K2=L[2],  K3=L[3],  K4=L[4],  K5=L[5],  K6=L[6],  K7=L[7],
        K8=L[8], K9=L[9], K10=L[10],K11=L[11],K12=L[12],K13=L[13],K14=L[14],K15=L[15];
    u64 w16 = ~0ULL;
    TOURNEY16(w16, lane)

    if (lane < KNN) merged[(wv<<4) + lane] = w16;
    __syncthreads();
    if (wv == 0){
      u64 out16 = merge64(merged, lane);
      write_outputs(out16, lane, n, idx_out, w_out);
    }
    __syncthreads();   // merged[] reused next slot
  }
}

// ---------------- GEMM: W-in-LDS (depth-2 prefetch) + A-in-registers ----------------
// r30-proven. Used for the two DUAL sage GEMMs.
template<int OUT, bool DUAL, bool BIAS, bool SPLITOUT>
__global__ __launch_bounds__(256, 4) void mm_mfma_r39(
    const unsigned short* __restrict__ A1h, const unsigned short* __restrict__ A1l,
    const unsigned short* __restrict__ A2h, const unsigned short* __restrict__ A2l,
    const unsigned short* __restrict__ W1h, const unsigned short* __restrict__ W1l,
    const unsigned short* __restrict__ W2h, const unsigned short* __restrict__ W2l,
    const float* __restrict__ bias,
    float* __restrict__ Cf, unsigned short* __restrict__ Ch, unsigned short* __restrict__ Cl)
{
  constexpr int NTILW = DUAL ? 4 : 2;      // W tiles per k-step
  constexpr int NW  = DUAL ? 4 : 2;        // W gload_lds per wave per step
  constexpr int NA  = DUAL ? 4 : 2;        // A register loads per lane per step
  constexpr int NCG = OUT / 64;            // 4 or 2
  constexpr int LG  = (NCG == 4) ? 2 : 1;
  constexpr int RTM = (NND + 63) / 64;     // 188
  __shared__ unsigned short sbW[3][NTILW][2048];   // 3 buffers x W tiles x 4KB
  const int lane = threadIdx.x & 63, wv = threadIdx.x >> 6;
  const int bid = blockIdx.x;
  const int xcd = bid & 7;
  const int cg  = (bid >> 3) & (NCG - 1);
  const int rt  = ((bid >> (3 + LG)) << 3) + xcd;
  if (rt >= RTM) return;
  const int row0 = rt*64;
  const int n0 = cg*64;
  const int l15 = lane & 15;
  const int quad = lane >> 4;

  const size_t woff = (size_t)(n0 + lane) * DM;
  const unsigned short* wsrc;
  int wtile, q0;
  if (DUAL){
    wsrc = ((wv==0) ? W1h : (wv==1) ? W1l : (wv==2) ? W2h : W2l) + woff;
    wtile = wv; q0 = 0;
  } else {
    wsrc = ((wv < 2) ? W1h : W1l) + woff;
    wtile = wv >> 1; q0 = (wv & 1) * 2;
  }

  const int am = min(row0 + wv*16 + l15, NND-1);
  const size_t abase = (size_t)am*DM + quad*8;

  f4_t acc[4];
  #pragma unroll
  for (int t=0;t<4;t++) acc[t] = (f4_t){0.f,0.f,0.f,0.f};

  bf8_t A1H[3], A1L[3], A2H[3], A2L[3];

  auto STAGE = [&](int b, int ks){
    if (DUAL){
      #pragma unroll
      for (int j=0;j<4;j++)
        gload16(wsrc + ks*32 + j*8, &sbW[b][wtile][j*512]);
    } else {
      #pragma unroll
      for (int j=0;j<2;j++)
        gload16(wsrc + ks*32 + (q0+j)*8, &sbW[b][wtile][(q0+j)*512]);
    }
  };
  auto LOADA = [&](int s, int ks){
    A1H[s] = *(const bf8_t*)(A1h + abase + ks*32);
    A1L[s] = *(const bf8_t*)(A1l + abase + ks*32);
    if (DUAL){
      A2H[s] = *(const bf8_t*)(A2h + abase + ks*32);
      A2L[s] = *(const bf8_t*)(A2l + abase + ks*32);
    }
  };

  STAGE(0, 0); LOADA(0, 0);
  STAGE(1, 1); LOADA(1, 1);
  constexpr int NKS = DM/32;             // 8
  #pragma unroll
  for (int ks=0; ks<NKS; ++ks){
    const int b = ks % 3;
    if (ks + 2 < NKS){ STAGE((ks+2)%3, ks+2); LOADA((ks+2)%3, ks+2); }
    if (ks + 2 < NKS)      asm volatile("s_waitcnt vmcnt(%0)" :: "i"(2*(NW+NA)) : "memory");
    else if (ks + 1 < NKS) asm volatile("s_waitcnt vmcnt(%0)" :: "i"(NW+NA) : "memory");
    else                   asm volatile("s_waitcnt vmcnt(0)" ::: "memory");
    __builtin_amdgcn_sched_barrier(0);
    __builtin_amdgcn_s_barrier();        // all waves: W tiles for ks complete
    __builtin_amdgcn_sched_barrier(0);
    {
      bf8_t a1h = A1H[b], a1l = A1L[b];
      bf8_t a2h, a2l;
      if (DUAL){ a2h = A2H[b]; a2l = A2L[b]; }
      #pragma unroll
      for (int t=0;t<4;t++){
        const int wr = quad*512 + (t*16 + l15)*8;
        bf8_t bh = *(const bf8_t*)&sbW[b][0][wr];
        bf8_t bl = *(const bf8_t*)&sbW[b][1][wr];
        acc[t] = __builtin_amdgcn_mfma_f32_16x16x32_bf16(a1h, bh, acc[t], 0, 0, 0);
        acc[t] = __builtin_amdgcn_mfma_f32_16x16x32_bf16(a1h, bl, acc[t], 0, 0, 0);
        acc[t] = __builtin_amdgcn_mfma_f32_16x16x32_bf16(a1l, bh, acc[t], 0, 0, 0);
        if (DUAL){
          bf8_t ch = *(const bf8_t*)&sbW[b][2][wr];
          bf8_t cl = *(const bf8_t*)&sbW[b][3][wr];
          acc[t] = __builtin_amdgcn_mfma_f32_16x16x32_bf16(a2h, ch, acc[t], 0, 0, 0);
          acc[t] = __builtin_amdgcn_mfma_f32_16x16x32_bf16(a2h, cl, acc[t], 0, 0, 0);
          acc[t] = __builtin_amdgcn_mfma_f32_16x16x32_bf16(a2l, ch, acc[t], 0, 0, 0);
        }
      }
    }
    __builtin_amdgcn_sched_barrier(0);
    asm volatile("s_waitcnt lgkmcnt(0)" ::: "memory");
    __builtin_amdgcn_s_barrier();        // all waves done reading buffer b
    __builtin_amdgcn_sched_barrier(0);
  }

  #pragma unroll
  for (int t=0;t<4;t++){
    int n = n0 + t*16 + l15;
    float bv = BIAS ? bias[n] : 0.f;
    #pragma unroll
    for (int r=0;r<4;r++){
      int row = row0 + wv*16 + quad*4 + r;
      if (row < NND){
        float v = geluf(acc[t][r] + bv);
        if (SPLITOUT){
          unsigned short hb = bf16_rne(v);
          float hf = __uint_as_float(((unsigned)hb) << 16);
          Ch[(size_t)row*OUT + n] = hb;
          Cl[(size_t)row*OUT + n] = bf16_rne(v - hf);
        } else {
          Cf[(size_t)row*OUT + n] = v;
        }
      }
    }
  }
}

// ---------------- CLASSIFIER: full-row GEMM + fused cls2 dot (r35-proven) ----------------
__global__ __launch_bounds__(256, 4) void cls_fused_r39(
    const unsigned short* __restrict__ A1h, const unsigned short* __restrict__ A1l,
    const unsigned short* __restrict__ W1h, const unsigned short* __restrict__ W1l,
    const float* __restrict__ bias, const float* __restrict__ w2,
    const float* __restrict__ b2,
    void* __restrict__ out, const int* __restrict__ flag)
{
  constexpr int NW = 4, NA = 2;            // vm ops per wave per step
  constexpr int RTM = (NND + 63) / 64;     // 188
  __shared__ unsigned short sbW[3][2][4096];   // 3 buf x {h,l} x 8KB (48KB)
  const int lane = threadIdx.x & 63, wv = threadIdx.x >> 6;
  const int bid = blockIdx.x;
  const int xcd = bid & 7;
  const int rt  = ((bid >> 3) << 3) + xcd;
  if (rt >= RTM) return;
  const int row0 = rt*64;
  const int l15 = lane & 15;
  const int quad = lane >> 4;

  const int am = min(row0 + wv*16 + l15, NND-1);
  const size_t abase = (size_t)am*DM + quad*8;

  f4_t acc[8];
  #pragma unroll
  for (int t=0;t<8;t++) acc[t] = (f4_t){0.f,0.f,0.f,0.f};

  bf8_t A1H[3], A1L[3];

  auto STAGE = [&](int b, int ks){
    #pragma unroll
    for (int j=0;j<4;j++){
      const int g = wv*4 + j;
      const int a = g >> 3, rem = g & 7, q = rem >> 1, half = rem & 1;
      const unsigned short* ws = (a ? W1l : W1h)
          + (size_t)(half*64 + lane)*DM + ks*32 + q*8;
      gload16(ws, &sbW[b][a][q*1024 + half*512]);
    }
  };
  auto LOADA = [&](int s, int ks){
    A1H[s] = *(const bf8_t*)(A1h + abase + ks*32);
    A1L[s] = *(const bf8_t*)(A1l + abase + ks*32);
  };

  STAGE(0, 0); LOADA(0, 0);
  STAGE(1, 1); LOADA(1, 1);
  constexpr int NKS = DM/32;             // 8
  #pragma unroll
  for (int ks=0; ks<NKS; ++ks){
    const int b = ks % 3;
    if (ks + 2 < NKS){ STAGE((ks+2)%3, ks+2); LOADA((ks+2)%3, ks+2); }
    if (ks + 2 < NKS)      asm volatile("s_waitcnt vmcnt(%0)" :: "i"(2*(NW+NA)) : "memory");
    else if (ks + 1 < NKS) asm volatile("s_waitcnt vmcnt(%0)" :: "i"(NW+NA) : "memory");
    else                   asm volatile("s_waitcnt vmcnt(0)" ::: "memory");
    __builtin_amdgcn_sched_barrier(0);
    __builtin_amdgcn_s_barrier();
    __builtin_amdgcn_sched_barrier(0);
    {
      bf8_t a1h = A1H[b], a1l = A1L[b];
      #pragma unroll
      for (int t=0;t<8;t++){
        const int wr = quad*1024 + (t*16 + l15)*8;
        bf8_t bh = *(const bf8_t*)&sbW[b][0][wr];
        bf8_t bl = *(const bf8_t*)&sbW[b][1][wr];
        acc[t] = __builtin_amdgcn_mfma_f32_16x16x32_bf16(a1h, bh, acc[t], 0, 0, 0);
        acc[t] = __builtin_amdgcn_mfma_f32_16x16x32_bf16(a1h, bl, acc[t], 0, 0, 0);
        acc[t] = __builtin_amdgcn_mfma_f32_16x16x32_bf16(a1l, bh, acc[t], 0, 0, 0);
      }
    }
    __builtin_amdgcn_sched_barrier(0);
    asm volatile("s_waitcnt lgkmcnt(0)" ::: "memory");
    __builtin_amdgcn_s_barrier();
    __builtin_amdgcn_sched_barrier(0);
  }

  // epilogue: gelu + dot(w2) + 16-lane reduce + sigmoid -> out
  const int is_bf16 = *flag;
  float partial0=0.f, partial1=0.f, partial2=0.f, partial3=0.f;
  #pragma unroll
  for (int t=0;t<8;t++){
    const int c = t*16 + l15;
    const float bv = bias[c];
    const float wc = w2[c];
    partial0 = fmaf(geluf(acc[t][0] + bv), wc, partial0);
    partial1 = fmaf(geluf(acc[t][1] + bv), wc, partial1);
    partial2 = fmaf(geluf(acc[t][2] + bv), wc, partial2);
    partial3 = fmaf(geluf(acc[t][3] + bv), wc, partial3);
  }
  #pragma unroll
  for (int o=1; o<16; o<<=1){
    partial0 += __shfl_xor(partial0, o, 64);
    partial1 += __shfl_xor(partial1, o, 64);
    partial2 += __shfl_xor(partial2, o, 64);
    partial3 += __shfl_xor(partial3, o, 64);
  }
  if (l15 == 0){
    const float bb = b2[0];
    #pragma unroll
    for (int r=0;r<4;r++){
      float s = (r==0)?partial0:(r==1)?partial1:(r==2)?partial2:partial3;
      int row = row0 + wv*16 + quad*4 + r;
      if (row < NND){
        float v = 1.0f / (1.0f + expf(-(s + bb)));
        if (is_bf16) ((__hip_bfloat16*)out)[row] = __float2bfloat16(v);
        else         ((float*)out)[row] = v;
      }
    }
  }
}

// ---------------- weighted neighbor aggregation ----------------
__global__ __launch_bounds__(256) void agg_kernel_r39(
    const unsigned short* __restrict__ hh, const unsigned short* __restrict__ hl,
    const int* __restrict__ idx, const float* __restrict__ w,
    unsigned short* __restrict__ oh, unsigned short* __restrict__ ol)
{
  const int lane = threadIdx.x & 63, wid = threadIdx.x >> 6;
  const int n = blockIdx.x*4 + wid;
  const int base = n*KNN;
  const int c = lane*4;
  float4 acc = make_float4(0.f,0.f,0.f,0.f);
  for (int k=0;k<KNN;k++){
    int j = idx[base+k];
    float wk = w[base+k];
    ushort4 vh = *(const ushort4*)(hh + (size_t)j*DM + c);
    ushort4 vl = *(const ushort4*)(hl + (size_t)j*DM + c);
    acc.x = fmaf(wk, bfpair(vh.x, vl.x), acc.x);
    acc.y = fmaf(wk, bfpair(vh.y, vl.y), acc.y);
    acc.z = fmaf(wk, bfpair(vh.z, vl.z), acc.z);
    acc.w = fmaf(wk, bfpair(vh.w, vl.w), acc.w);
  }
  unsigned short h0 = bf16_rne(acc.x); float f0 = __uint_as_float(((unsigned)h0) << 16);
  unsigned short h1 = bf16_rne(acc.y); float f1 = __uint_as_float(((unsigned)h1) << 16);
  unsigned short h2 = bf16_rne(acc.z); float f2 = __uint_as_float(((unsigned)h2) << 16);
  unsigned short h3 = bf16_rne(acc.w); float f3 = __uint_as_float(((unsigned)h3) << 16);
  ushort4 sh = make_ushort4(h0, h1, h2, h3);
  ushort4 sl = make_ushort4(bf16_rne(acc.x - f0), bf16_rne(acc.y - f1),
                            bf16_rne(acc.z - f2), bf16_rne(acc.w - f3));
  *(ushort4*)(oh + (size_t)n*DM + c) = sh;
  *(ushort4*)(ol + (size_t)n*DM + c) = sl;
}

// ---------------- h = h + layernorm(tmp)*g + b  (h stored as bf16 hi/lo) ----------------
__global__ __launch_bounds__(256) void ln_res_kernel_r39(
    unsigned short* __restrict__ hh, unsigned short* __restrict__ hl,
    const float* __restrict__ tmp, const float* __restrict__ g, const float* __restrict__ b)
{
  const int lane = threadIdx.x & 63, wid = threadIdx.x >> 6;
  const int n = blockIdx.x*4 + wid;
  float4 x = *(const float4*)(tmp + (size_t)n*DM + lane*4);
  float s = (x.x + x.y) + (x.z + x.w);
  #pragma unroll
  for (int off=32; off>0; off>>=1) s += __shfl_xor(s, off, 64);
  float mu = s * (1.0f/DM);
  float dx0 = x.x-mu, dx1 = x.y-mu, dx2 = x.z-mu, dx3 = x.w-mu;
  float v = (dx0*dx0 + dx1*dx1) + (dx2*dx2 + dx3*dx3);
  #pragma unroll
  for (int off=32; off>0; off>>=1) v += __shfl_xor(v, off, 64);
  float rs = 1.0f / sqrtf(v * (1.0f/DM) + 1e-5f);
  int c = lane*4;
  float4 gv = *(const float4*)(g + c);
  float4 bv = *(const float4*)(b + c);
  ushort4 vh = *(const ushort4*)(hh + (size_t)n*DM + c);
  ushort4 vl = *(const ushort4*)(hl + (size_t)n*DM + c);
  float o0 = bfpair(vh.x, vl.x) + dx0*rs*gv.x + bv.x;
  float o1 = bfpair(vh.y, vl.y) + dx1*rs*gv.y + bv.y;
  float o2 = bfpair(vh.z, vl.z) + dx2*rs*gv.z + bv.z;
  float o3 = bfpair(vh.w, vl.w) + dx3*rs*gv.w + bv.w;
  unsigned short h0 = bf16_rne(o0); float f0 = __uint_as_float(((unsigned)h0) << 16);
  unsigned short h1 = bf16_rne(o1); float f1 = __uint_as_float(((unsigned)h1) << 16);
  unsigned short h2 = bf16_rne(o2); float f2 = __uint_as_float(((unsigned)h2) << 16);
  unsigned short h3 = bf16_rne(o3); float f3 = __uint_as_float(((unsigned)h3) << 16);
  *(ushort4*)(hh + (size_t)n*DM + c) = make_ushort4(h0, h1, h2, h3);
  *(ushort4*)(hl + (size_t)n*DM + c) = make_ushort4(bf16_rne(o0 - f0), bf16_rne(o1 - f1),
                                                    bf16_rne(o2 - f2), bf16_rne(o3 - f3));
}

extern "C" void kernel_launch(void* const* d_in, const int* in_sizes, int n_in,
                              void* d_out, int out_size, void* d_ws, size_t ws_size,
                              hipStream_t stream)
{
  // ---- workspace layout (~46.6 MB), fully rewritten every call ----
  char* base = (char*)d_ws;
  int*   flag = (int*)base;                                   // 16 B slot
  float* wreg = (float*)(base + 16);
  static const int sizes[16] = {
    NND*256, NND*2, 256*256, 256, 256*256, 256*256, 256, 256,
    256*256, 256*256, 256, 256, 128*256, 128, 128, 1
  };
  float* ptrs[16];
  {
    float* p = wreg;
    for (int i = 2; i < 16; i++){ ptrs[i] = p; p += (sizes[i] + 3) & ~3; }
    ptrs[1] = p;                          // cents  [24,000]
    p += NND*2;
    ptrs[0] = p;                          // feats region  [3,072,000 floats]
  }
  float* F    = ptrs[0];                  // f32 tmp view of feats region
  unsigned short* fh = (unsigned short*)ptrs[0];          // feats hi
  unsigned short* fl = fh + (size_t)NND*DM;               // feats lo
  float* C    = ptrs[1];
  float* hbase = F + (size_t)NND*DM;
  unsigned short* h_hi = (unsigned short*)hbase;
  unsigned short* h_lo = h_hi + (size_t)NND*DM;
  float* abase = hbase + (size_t)NND*DM;
  unsigned short* a_hi = (unsigned short*)abase;
  unsigned short* a_lo = a_hi + (size_t)NND*DM;
  float* hid  = abase + (size_t)NND*DM;   // (region retained; cls2 fused away)
  int*  gidx  = (int*)(hid + (size_t)NND*128);
  float* gw   = (float*)(gidx + (size_t)NND*KNN);
  // knn pre-pass scratch (packed float4 candidates)
  float4* sxyid = (float4*)(gw + (size_t)NND*KNN);
  int*    hist  = (int*)(sxyid + NND);
  int*    cursor= hist + NB;
  int*    offs  = cursor + NB;
  int*    ocnt  = offs + NB;
  int*    olist = ocnt + 4;               // 16B pad keeps wh 16B-aligned
  float*  othr  = (float*)(olist + NND);  // thr per deferred node
  // bf16 hi/lo weights (enc_w | g1_ws | g1_wn | g2_ws | g2_wn | cls_w1), 16B-aligned
  unsigned short* wh = (unsigned short*)(((uintptr_t)(othr + NND) + 15) & ~(uintptr_t)15);
  unsigned short* wl = wh + NWELEM;

  // ---- dtype detect + decode (weights split to hi/lo IN decode; r34-proven) ----
  detect_kernel_r39<<<1, 256, 0, stream>>>((const unsigned*)d_in[1], 4096,
                                           (const unsigned*)d_in[0], 16384, flag);
  SegTable t;
  int total = 0;
  for (int i = 0; i < 16; i++){
    t.src[i] = d_in[i];
    t.dst[i] = ptrs[i];
    t.cnt[i] = sizes[i];
    t.wofs[i] = -1;
    total += sizes[i];
  }
  t.dst[0] = nullptr;       // feats handled via fh/fl
  t.wofs[2]  = 0;           // enc_w
  t.wofs[4]  = 65536;       // g1_ws
  t.wofs[5]  = 131072;      // g1_wn
  t.wofs[8]  = 196608;      // g2_ws
  t.wofs[9]  = 262144;      // g2_wn
  t.wofs[12] = 327680;      // cls_w1
  t.total = total;
  decode_kernel_r39<<<(total + 255)/256, 256, 0, stream>>>(t, fh, fl, wh, wl, flag);

  const float* enc_b  = ptrs[3];
  const float* g1_g   = ptrs[6];  const float* g1_b   = ptrs[7];
  const float* g2_g   = ptrs[10]; const float* g2_b   = ptrs[11];
  const float* cls_b1 = ptrs[13];
  const float* cls_w2 = ptrs[14]; const float* cls_b2 = ptrs[15];

  dim3 b256(256);
  // knn pre-pass: bucket counting sort by x (+ zero outlier counter)
  zero_kernel_r39<<<(NB + 255)/256, b256, 0, stream>>>(hist, cursor, ocnt);
  count_kernel_r39<<<(NND + 255)/256, b256, 0, stream>>>(C, hist);
  scan_kernel_r39<<<1, 1024, 0, stream>>>(hist, offs);
  scatter_kernel_r39<<<(NND + 255)/256, b256, 0, stream>>>(C, offs, cursor, sxyid);
  // swizzled grids: 24 rt-groups of 8 XCD-slots x NCG col-groups
  const int G4 = 24 * 8 * 4;   // 768  (OUT=256)
  // FUSED: knn_fixed (blocks 0..2999) || encoder GEMM (blocks 3000..3767)
  fused_enc_knn_r39<<<KBLK + G4, b256, 0, stream>>>(
      fh, fl, wh + 0, wl + 0, enc_b, h_hi, h_lo,
      sxyid, C, offs, gidx, gw, ocnt, olist, othr);
  knn_ext_r39<<<2048, b256, 0, stream>>>(sxyid, C, offs, olist, othr, ocnt, gidx, gw);
  // sage layer 1 (tmp := F region, feats dead after encoder)
  agg_kernel_r39<<<NND/4, b256, 0, stream>>>(h_hi, h_lo, gidx, gw, a_hi, a_lo);
  mm_mfma_r39<256,true,false,false><<<G4, b256, 0, stream>>>(h_hi, h_lo, a_hi, a_lo,
      wh + 65536, wl + 65536, wh + 131072, wl + 131072, nullptr, F, nullptr, nullptr);
  ln_res_kernel_r39<<<NND/4, b256, 0, stream>>>(h_hi, h_lo, F, g1_g, g1_b);
  // sage layer 2
  agg_kernel_r39<<<NND/4, b256, 0, stream>>>(h_hi, h_lo, gidx, gw, a_hi, a_lo);
  mm_mfma_r39<256,true,false,false><<<G4, b256, 0, stream>>>(h_hi, h_lo, a_hi, a_lo,
      wh + 196608, wl + 196608, wh + 262144, wl + 262144, nullptr, F, nullptr, nullptr);
  ln_res_kernel_r39<<<NND/4, b256, 0, stream>>>(h_hi, h_lo, F, g2_g, g2_b);
  // classifier: full-row GEMM + fused cls2 dot -> d_out (192 blocks)
  cls_fused_r39<<<24*8, b256, 0, stream>>>(h_hi, h_lo,
      wh + 327680, wl + 327680, cls_b1, cls_w2, cls_b2, d_out, flag);
}